// Round 3
// baseline (434.658 us; speedup 1.0000x reference)
//
#include <hip/hip_runtime.h>

#define NN 100000
#define NE 640000
#define DD 128
#define ROUNDS 4
#define CAP 32          // max in-degree; deg ≈ Poisson(6.4); P(any overflow) ~ 1e-9
#define NFT 3125        // NN / 32  (32-row tiles)
#define GEMMB 1024      // prep_k grid (3 blocks/CU resident = 768; rest backfill)
#define FG 1024         // gemm_round_k grid
#define KPH 136         // LDS row stride in halves (272 B; 2-way bank alias free)

typedef float f32x4 __attribute__((ext_vector_type(4)));
typedef _Float16 half8 __attribute__((ext_vector_type(8)));

// ---------------------------------------------------------------------------
// Weight prep: W (128x128 fp32 [k][n]) -> WT fp16 [n][k].
// mats: 0=Wi, 1..4=Wm[0..3], 5..8=Wu[0..3].
// ---------------------------------------------------------------------------
__global__ __launch_bounds__(128) void wprep_k(
    const float* __restrict__ Wi, const float* __restrict__ Wm,
    const float* __restrict__ Wu, _Float16* __restrict__ WT)
{
    const int mat = blockIdx.x >> 7;
    const int k   = blockIdx.x & 127;
    const int n   = threadIdx.x;
    const float* W = (mat == 0) ? Wi
                   : (mat <= 4) ? Wm + (size_t)(mat - 1) * DD * DD
                                : Wu + (size_t)(mat - 5) * DD * DD;
    WT[(size_t)mat * DD * DD + (size_t)n * DD + k] = (_Float16)W[(size_t)k * DD + n];
}

// ---------------------------------------------------------------------------
// prep_k: bucket-build prologue + 32-row-tile GEMM chain:
//   S0 = relu(x @ Wi + bi) -> Sh;  msg0 = relu(S0 @ Wm0 + bm0) -> msgA
// Weight DEDUP: each wave owns a distinct 32-col slice (WI/WM = 2x32 regs,
// was 2x64 duplicated) -> ~130 live regs -> 3 blocks/CU (was 2).
// x staged via LDS coalesced (old per-lane [row][k] reads were 4x sector waste).
// ---------------------------------------------------------------------------
__global__ __launch_bounds__(256, 3) void prep_k(
    const float* __restrict__ x,
    const _Float16* __restrict__ WiT, const _Float16* __restrict__ Wm0T,
    const float* __restrict__ bi, const float* __restrict__ bm0,
    _Float16* __restrict__ Sh, _Float16* __restrict__ msg0,
    const int* __restrict__ src, const int* __restrict__ dst,
    int* __restrict__ cursor, int* __restrict__ bucket)
{
    // ---- bucket-build prologue (all blocks) ----
    for (int e = blockIdx.x * 256 + threadIdx.x; e < NE; e += GEMMB * 256) {
        const int d = dst[e];
        const int s = src[e];
        const int pos = atomicAdd(&cursor[d], 1);
        if (pos < CAP) bucket[(long long)d * CAP + pos] = s;
    }

    __shared__ _Float16 Ash[32 * KPH];

    const int tid  = threadIdx.x;
    const int lane = tid & 63;
    const int wave = tid >> 6;
    const int ln   = lane & 15;
    const int q    = lane >> 4;
    const int colBase = wave * 32;        // dedup: distinct 32-col slice per wave

    half8 WI[4][2], WM[4][2];
#pragma unroll
    for (int s = 0; s < 4; s++)
#pragma unroll
        for (int b = 0; b < 2; b++) {
            const size_t off = (size_t)(colBase + b * 16 + ln) * DD + s * 32 + q * 8;
            WI[s][b] = *(const half8*)&WiT[off];
            WM[s][b] = *(const half8*)&Wm0T[off];
        }
    float biasi[2], biasm[2];
#pragma unroll
    for (int b = 0; b < 2; b++) {
        biasi[b] = bi[colBase + b * 16 + ln];
        biasm[b] = bm0[colBase + b * 16 + ln];
    }

    const int grow = tid >> 3;     // 0..31
    const int grp  = tid & 7;      // 0..7
    const int gcol = grp * 16;

    for (int tileB = blockIdx.x; tileB < NFT; tileB += GEMMB) {
        // ---- stage x tile -> Ash fp16 (coalesced 64 B/thread) ----
        const float* xr = x + ((size_t)tileB * 32 + grow) * DD + gcol;
        const float4 f0 = *(const float4*)&xr[0];
        const float4 f1 = *(const float4*)&xr[4];
        const float4 f2 = *(const float4*)&xr[8];
        const float4 f3 = *(const float4*)&xr[12];
        half8 hx0, hx1;
        hx0[0] = (_Float16)f0.x; hx0[1] = (_Float16)f0.y;
        hx0[2] = (_Float16)f0.z; hx0[3] = (_Float16)f0.w;
        hx0[4] = (_Float16)f1.x; hx0[5] = (_Float16)f1.y;
        hx0[6] = (_Float16)f1.z; hx0[7] = (_Float16)f1.w;
        hx1[0] = (_Float16)f2.x; hx1[1] = (_Float16)f2.y;
        hx1[2] = (_Float16)f2.z; hx1[3] = (_Float16)f2.w;
        hx1[4] = (_Float16)f3.x; hx1[5] = (_Float16)f3.y;
        hx1[6] = (_Float16)f3.z; hx1[7] = (_Float16)f3.w;

        __syncthreads();   // prior tile's phase-3 Ash reads done
        *(half8*)&Ash[grow * KPH + gcol]     = hx0;
        *(half8*)&Ash[grow * KPH + gcol + 8] = hx1;
        __syncthreads();

        // ---- GEMM1: S0 = relu(x @ Wi + bi) ----
        f32x4 acc[2][2];
#pragma unroll
        for (int h = 0; h < 2; h++)
#pragma unroll
            for (int b = 0; b < 2; b++)
                acc[h][b] = (f32x4){biasi[b], biasi[b], biasi[b], biasi[b]};
#pragma unroll
        for (int s = 0; s < 4; s++) {
            const half8 a0 = *(const half8*)&Ash[(ln)      * KPH + s * 32 + q * 8];
            const half8 a1 = *(const half8*)&Ash[(16 + ln) * KPH + s * 32 + q * 8];
#pragma unroll
            for (int b = 0; b < 2; b++) {
                acc[0][b] = __builtin_amdgcn_mfma_f32_16x16x32_f16(a0, WI[s][b], acc[0][b], 0, 0, 0);
                acc[1][b] = __builtin_amdgcn_mfma_f32_16x16x32_f16(a1, WI[s][b], acc[1][b], 0, 0, 0);
            }
        }
        __syncthreads();   // all A-reads of x done before overwrite

        // S0 = relu(acc): write Sh + restage to LDS
#pragma unroll
        for (int h = 0; h < 2; h++)
#pragma unroll
            for (int b = 0; b < 2; b++) {
                const int col = colBase + b * 16 + ln;
#pragma unroll
                for (int r = 0; r < 4; r++) {
                    const int lrow = h * 16 + q * 4 + r;
                    const size_t row = (size_t)tileB * 32 + lrow;
                    const _Float16 v = (_Float16)fmaxf(acc[h][b][r], 0.f);
                    Sh[row * DD + col] = v;
                    Ash[lrow * KPH + col] = v;
                }
            }
        __syncthreads();

        // ---- GEMM2: msg0 = relu(S0 @ Wm0 + bm0) ----
        f32x4 acc2[2][2];
#pragma unroll
        for (int h = 0; h < 2; h++)
#pragma unroll
            for (int b = 0; b < 2; b++)
                acc2[h][b] = (f32x4){biasm[b], biasm[b], biasm[b], biasm[b]};
#pragma unroll
        for (int s = 0; s < 4; s++) {
            const half8 a0 = *(const half8*)&Ash[(ln)      * KPH + s * 32 + q * 8];
            const half8 a1 = *(const half8*)&Ash[(16 + ln) * KPH + s * 32 + q * 8];
#pragma unroll
            for (int b = 0; b < 2; b++) {
                acc2[0][b] = __builtin_amdgcn_mfma_f32_16x16x32_f16(a0, WM[s][b], acc2[0][b], 0, 0, 0);
                acc2[1][b] = __builtin_amdgcn_mfma_f32_16x16x32_f16(a1, WM[s][b], acc2[1][b], 0, 0, 0);
            }
        }
#pragma unroll
        for (int h = 0; h < 2; h++)
#pragma unroll
            for (int b = 0; b < 2; b++) {
                const int col = colBase + b * 16 + ln;
#pragma unroll
                for (int r = 0; r < 4; r++) {
                    const size_t row = (size_t)tileB * 32 + h * 16 + q * 4 + r;
                    msg0[row * DD + col] = (_Float16)fmaxf(acc2[h][b][r], 0.f);
                }
            }
    }
}

// ---------------------------------------------------------------------------
// gather_k: agg[node] = sum_{s in bucket[node]} msgIn[s]   (fp16 rows)
// Pure gather-sum: no LDS, no barriers, no weights -> ~65 regs -> ~7 waves/SIMD
// (~28 waves/CU): 4x the in-flight random loads of the fused version — this is
// the Little's-law fix for the random-row read stream.
// One block per 32 nodes; 8 threads per node (16 cols each); masked 4-wide.
// ---------------------------------------------------------------------------
__global__ __launch_bounds__(256, 4) void gather_k(
    const _Float16* __restrict__ msgIn,
    const int* __restrict__ cursor,
    const int* __restrict__ bucket,
    _Float16* __restrict__ agg)
{
    const int tid  = threadIdx.x;
    const int lane = tid & 63;
    const int grow = tid >> 3;     // 0..31
    const int grp  = tid & 7;      // 0..7
    const int gcol = grp * 16;

    const int node = blockIdx.x * 32 + grow;   // grid = NFT exactly covers NN
    int cnt = cursor[node];
    if (cnt > CAP) cnt = CAP;

    int idxr[4];
    const int ibase = node * CAP;
#pragma unroll
    for (int i = 0; i < 4; i++) idxr[i] = bucket[ibase + grp + 8 * i];

    float a[16];
#pragma unroll
    for (int i = 0; i < 16; i++) a[i] = 0.f;

    for (int j = 0; j < cnt; j += 4) {
        int ix[4];
#pragma unroll
        for (int u = 0; u < 4; u++) {
            const int jj = (j + u) & 31;           // wrap keeps idxr idx valid
            int v = __shfl(idxr[jj >> 3], (lane & 56) | (jj & 7), 64);
            ix[u] = ((unsigned)v < NN) ? v : 0;    // clamp speculative lanes
        }
        half8 v[8];
#pragma unroll
        for (int u = 0; u < 4; u++) {
            v[2 * u]     = *(const half8*)&msgIn[(size_t)ix[u] * DD + gcol];
            v[2 * u + 1] = *(const half8*)&msgIn[(size_t)ix[u] * DD + gcol + 8];
        }
#pragma unroll
        for (int u = 0; u < 4; u++) {
            if (j + u < cnt) {                      // exec-masked accumulate
#pragma unroll
                for (int i = 0; i < 8; i++) {
                    a[i]     += (float)v[2 * u][i];
                    a[8 + i] += (float)v[2 * u + 1][i];
                }
            }
        }
    }

    half8 h0, h1;
#pragma unroll
    for (int i = 0; i < 8; i++) { h0[i] = (_Float16)a[i]; h1[i] = (_Float16)a[8 + i]; }
    *(half8*)&agg[(size_t)node * DD + gcol]     = h0;
    *(half8*)&agg[(size_t)node * DD + gcol + 8] = h1;
}

// ---------------------------------------------------------------------------
// gemm_round_k (one dispatch per round, after gather_k):
//   Snew = Sold + relu( agg @ Wu + bu )
//   if WmT:  msgOut = relu( Snew @ Wm_next + bm_next )
//   else:    write fp32 Of (final round)
// msgOut may ALIAS agg (each row is read into Ash before that block writes it;
// tiles are block-disjoint) -> no extra workspace. Hence no __restrict__ on
// agg/msgOut. Weight dedup as in prep_k -> 3 blocks/CU.
// ---------------------------------------------------------------------------
__global__ __launch_bounds__(256, 3) void gemm_round_k(
    const _Float16* agg,
    const _Float16* __restrict__ WuT, const float* __restrict__ bu_r,
    const _Float16* __restrict__ WmT, const float* __restrict__ bm_r,
    const _Float16* __restrict__ Rh,
    _Float16* __restrict__ ShOut,
    _Float16* msgOut,
    float* __restrict__ Of)
{
    __shared__ _Float16 Ash[32 * KPH];

    const int tid  = threadIdx.x;
    const int lane = tid & 63;
    const int wave = tid >> 6;
    const int ln   = lane & 15;
    const int q    = lane >> 4;
    const int colBase = wave * 32;        // dedup slice

    half8 WU[4][2], WM[4][2];
#pragma unroll
    for (int s = 0; s < 4; s++)
#pragma unroll
        for (int b = 0; b < 2; b++) {
            const size_t off = (size_t)(colBase + b * 16 + ln) * DD + s * 32 + q * 8;
            WU[s][b] = *(const half8*)&WuT[off];
            if (WmT) WM[s][b] = *(const half8*)&WmT[off];
        }
    float biasu[2], biasm[2];
#pragma unroll
    for (int b = 0; b < 2; b++) {
        biasu[b] = bu_r[colBase + b * 16 + ln];
        biasm[b] = WmT ? bm_r[colBase + b * 16 + ln] : 0.f;
    }

    const int grow = tid >> 3;
    const int grp  = tid & 7;
    const int gcol = grp * 16;

    for (int tileB = blockIdx.x; tileB < NFT; tileB += gridDim.x) {
        // ---- stage agg tile -> Ash (coalesced) ----
        const _Float16* ar = agg + ((size_t)tileB * 32 + grow) * DD + gcol;
        const half8 g0 = *(const half8*)&ar[0];
        const half8 g1 = *(const half8*)&ar[8];

        __syncthreads();   // prior tile's last Ash reads done
        *(half8*)&Ash[grow * KPH + gcol]     = g0;
        *(half8*)&Ash[grow * KPH + gcol + 8] = g1;
        __syncthreads();

        // ---- GEMM1: t = agg @ Wu + bu ----
        f32x4 acc[2][2];
#pragma unroll
        for (int h = 0; h < 2; h++)
#pragma unroll
            for (int b = 0; b < 2; b++)
                acc[h][b] = (f32x4){biasu[b], biasu[b], biasu[b], biasu[b]};
#pragma unroll
        for (int s = 0; s < 4; s++) {
            const half8 a0 = *(const half8*)&Ash[(ln)      * KPH + s * 32 + q * 8];
            const half8 a1 = *(const half8*)&Ash[(16 + ln) * KPH + s * 32 + q * 8];
#pragma unroll
            for (int b = 0; b < 2; b++) {
                acc[0][b] = __builtin_amdgcn_mfma_f32_16x16x32_f16(a0, WU[s][b], acc[0][b], 0, 0, 0);
                acc[1][b] = __builtin_amdgcn_mfma_f32_16x16x32_f16(a1, WU[s][b], acc[1][b], 0, 0, 0);
            }
        }

        if (!WmT) {
            // final round: fp32 output only (Rh read inline, L3-hot)
#pragma unroll
            for (int h = 0; h < 2; h++)
#pragma unroll
                for (int b = 0; b < 2; b++) {
                    const int col = colBase + b * 16 + ln;
#pragma unroll
                    for (int r = 0; r < 4; r++) {
                        const size_t row = (size_t)tileB * 32 + h * 16 + q * 4 + r;
                        Of[row * DD + col] = fmaxf(acc[h][b][r], 0.f) + (float)Rh[row * DD + col];
                    }
                }
            continue;   // loop-top barrier guards Ash reads
        }

        __syncthreads();   // all agg A-reads done before overwrite
        // Snew = Sold + relu(acc): write ShOut + restage to LDS
#pragma unroll
        for (int h = 0; h < 2; h++)
#pragma unroll
            for (int b = 0; b < 2; b++) {
                const int col = colBase + b * 16 + ln;
#pragma unroll
                for (int r = 0; r < 4; r++) {
                    const int lrow = h * 16 + q * 4 + r;
                    const size_t row = (size_t)tileB * 32 + lrow;
                    const _Float16 v =
                        (_Float16)(fmaxf(acc[h][b][r], 0.f) + (float)Rh[row * DD + col]);
                    ShOut[row * DD + col] = v;
                    Ash[lrow * KPH + col] = v;
                }
            }
        __syncthreads();

        // ---- GEMM2: msgOut = relu(Snew @ Wm_next + bm_next) ----
        f32x4 acc2[2][2];
#pragma unroll
        for (int h = 0; h < 2; h++)
#pragma unroll
            for (int b = 0; b < 2; b++)
                acc2[h][b] = (f32x4){biasm[b], biasm[b], biasm[b], biasm[b]};
#pragma unroll
        for (int s = 0; s < 4; s++) {
            const half8 a0 = *(const half8*)&Ash[(ln)      * KPH + s * 32 + q * 8];
            const half8 a1 = *(const half8*)&Ash[(16 + ln) * KPH + s * 32 + q * 8];
#pragma unroll
            for (int b = 0; b < 2; b++) {
                acc2[0][b] = __builtin_amdgcn_mfma_f32_16x16x32_f16(a0, WM[s][b], acc2[0][b], 0, 0, 0);
                acc2[1][b] = __builtin_amdgcn_mfma_f32_16x16x32_f16(a1, WM[s][b], acc2[1][b], 0, 0, 0);
            }
        }
#pragma unroll
        for (int h = 0; h < 2; h++)
#pragma unroll
            for (int b = 0; b < 2; b++) {
                const int col = colBase + b * 16 + ln;
#pragma unroll
                for (int r = 0; r < 4; r++) {
                    const size_t row = (size_t)tileB * 32 + h * 16 + q * 4 + r;
                    msgOut[row * DD + col] = (_Float16)fmaxf(acc2[h][b][r], 0.f);
                }
            }
    }
}

extern "C" void kernel_launch(void* const* d_in, const int* in_sizes, int n_in,
                              void* d_out, int out_size, void* d_ws, size_t ws_size,
                              hipStream_t stream) {
    const float* x  = (const float*)d_in[0];
    const int*   ei = (const int*)d_in[1];
    const float* Wi = (const float*)d_in[2];
    const float* bi = (const float*)d_in[3];
    const float* Wm = (const float*)d_in[4];
    const float* bm = (const float*)d_in[5];
    const float* Wu = (const float*)d_in[6];
    const float* bu = (const float*)d_in[7];

    const int* src = ei;           // edge_index[0] : gather source
    const int* dst = ei + NE;      // edge_index[1] : aggregation target

    // Workspace carve (~91 MB):
    const size_t NELE = (size_t)NN * DD;
    _Float16* msgA = (_Float16*)d_ws;                    // 25.6 MB
    _Float16* msgB = msgA + NELE;                        // 25.6 MB
    _Float16* Sh   = msgB + NELE;                        // 25.6 MB
    _Float16* WT   = Sh + NELE;                          // 288 KB (9 mats)
    int* cursor = (int*)(WT + 9 * DD * DD);              // 400 KB
    int* bucket = cursor + NN;                           // 12.8 MB

    hipMemsetAsync(cursor, 0, (size_t)NN * 4, stream);
    wprep_k<<<9 * 128, 128, 0, stream>>>(Wi, Wm, Wu, WT);

    // input GEMM (+ msg0 GEMM) + bucket build (prologue), one dispatch
    prep_k<<<GEMMB, 256, 0, stream>>>(
        x, WT /*Wi*/, WT + 1 * DD * DD /*Wm0*/, bi, bm,
        Sh, msgA, src, dst, cursor, bucket);

    _Float16* mIn = msgA;
    _Float16* mOut = msgB;
    for (int r = 0; r < ROUNDS; r++) {
        const bool last = (r == ROUNDS - 1);
        // agg lands in mOut, then gemm_round_k reads it and overwrites it with
        // the next messages (row-wise read-before-write within each block).
        gather_k<<<NFT, 256, 0, stream>>>(mIn, cursor, bucket, mOut);
        gemm_round_k<<<FG, 256, 0, stream>>>(
            mOut /*agg*/,
            WT + (size_t)(5 + r) * DD * DD, bu + (size_t)r * DD,
            last ? nullptr : WT + (size_t)(2 + r) * DD * DD,   // Wm[r+1]
            last ? nullptr : bm + (size_t)(r + 1) * DD,
            Sh, Sh,
            mOut /*msgOut aliases agg*/,
            last ? (float*)d_out : nullptr);
        _Float16* t = mIn; mIn = mOut; mOut = t;
    }
}

// Round 4
// 392.889 us; speedup vs baseline: 1.1063x; 1.1063x over previous
//
#include <hip/hip_runtime.h>

#define NN 100000
#define NE 640000
#define DD 128
#define ROUNDS 4
#define CAP 32          // max in-degree; deg ≈ Poisson(6.4); P(any overflow) ~ 1e-9
#define NFT 3125        // NN / 32  (32-row tiles)
#define GEMMB 1024      // prep_k grid
#define FG 768          // fused grid: 3 blocks/CU x 256 CU, exactly resident
#define KPH 136         // LDS row stride in halves (272 B; 2-way bank alias free)

typedef float f32x4 __attribute__((ext_vector_type(4)));
typedef _Float16 half8 __attribute__((ext_vector_type(8)));

// ---------------------------------------------------------------------------
// Weight prep: W (128x128 fp32 [k][n]) -> WT fp16 [n][k].
// mats: 0=Wi, 1..4=Wm[0..3], 5..8=Wu[0..3].
// ---------------------------------------------------------------------------
__global__ __launch_bounds__(128) void wprep_k(
    const float* __restrict__ Wi, const float* __restrict__ Wm,
    const float* __restrict__ Wu, _Float16* __restrict__ WT)
{
    const int mat = blockIdx.x >> 7;
    const int k   = blockIdx.x & 127;
    const int n   = threadIdx.x;
    const float* W = (mat == 0) ? Wi
                   : (mat <= 4) ? Wm + (size_t)(mat - 1) * DD * DD
                                : Wu + (size_t)(mat - 5) * DD * DD;
    WT[(size_t)mat * DD * DD + (size_t)n * DD + k] = (_Float16)W[(size_t)k * DD + n];
}

// ---------------------------------------------------------------------------
// prep_k (R3 form, 79 us): bucket-build prologue + 32-row-tile GEMM chain:
//   S0 = relu(x @ Wi + bi) -> Sh;  msg0 = relu(S0 @ Wm0 + bm0) -> msgA
// Weight dedup: each wave owns a distinct 32-col slice -> 3 blocks/CU.
// ---------------------------------------------------------------------------
__global__ __launch_bounds__(256, 3) void prep_k(
    const float* __restrict__ x,
    const _Float16* __restrict__ WiT, const _Float16* __restrict__ Wm0T,
    const float* __restrict__ bi, const float* __restrict__ bm0,
    _Float16* __restrict__ Sh, _Float16* __restrict__ msg0,
    const int* __restrict__ src, const int* __restrict__ dst,
    int* __restrict__ cursor, int* __restrict__ bucket)
{
    // ---- bucket-build prologue (all blocks) ----
    for (int e = blockIdx.x * 256 + threadIdx.x; e < NE; e += GEMMB * 256) {
        const int d = dst[e];
        const int s = src[e];
        const int pos = atomicAdd(&cursor[d], 1);
        if (pos < CAP) bucket[(long long)d * CAP + pos] = s;
    }

    __shared__ _Float16 Ash[32 * KPH];

    const int tid  = threadIdx.x;
    const int lane = tid & 63;
    const int wave = tid >> 6;
    const int ln   = lane & 15;
    const int q    = lane >> 4;
    const int colBase = wave * 32;        // dedup: distinct 32-col slice per wave

    half8 WI[4][2], WM[4][2];
#pragma unroll
    for (int s = 0; s < 4; s++)
#pragma unroll
        for (int b = 0; b < 2; b++) {
            const size_t off = (size_t)(colBase + b * 16 + ln) * DD + s * 32 + q * 8;
            WI[s][b] = *(const half8*)&WiT[off];
            WM[s][b] = *(const half8*)&Wm0T[off];
        }
    float biasi[2], biasm[2];
#pragma unroll
    for (int b = 0; b < 2; b++) {
        biasi[b] = bi[colBase + b * 16 + ln];
        biasm[b] = bm0[colBase + b * 16 + ln];
    }

    const int grow = tid >> 3;     // 0..31
    const int grp  = tid & 7;      // 0..7
    const int gcol = grp * 16;

    for (int tileB = blockIdx.x; tileB < NFT; tileB += GEMMB) {
        // ---- stage x tile -> Ash fp16 (coalesced 64 B/thread) ----
        const float* xr = x + ((size_t)tileB * 32 + grow) * DD + gcol;
        const float4 f0 = *(const float4*)&xr[0];
        const float4 f1 = *(const float4*)&xr[4];
        const float4 f2 = *(const float4*)&xr[8];
        const float4 f3 = *(const float4*)&xr[12];
        half8 hx0, hx1;
        hx0[0] = (_Float16)f0.x; hx0[1] = (_Float16)f0.y;
        hx0[2] = (_Float16)f0.z; hx0[3] = (_Float16)f0.w;
        hx0[4] = (_Float16)f1.x; hx0[5] = (_Float16)f1.y;
        hx0[6] = (_Float16)f1.z; hx0[7] = (_Float16)f1.w;
        hx1[0] = (_Float16)f2.x; hx1[1] = (_Float16)f2.y;
        hx1[2] = (_Float16)f2.z; hx1[3] = (_Float16)f2.w;
        hx1[4] = (_Float16)f3.x; hx1[5] = (_Float16)f3.y;
        hx1[6] = (_Float16)f3.z; hx1[7] = (_Float16)f3.w;

        __syncthreads();   // prior tile's phase-3 Ash reads done
        *(half8*)&Ash[grow * KPH + gcol]     = hx0;
        *(half8*)&Ash[grow * KPH + gcol + 8] = hx1;
        __syncthreads();

        // ---- GEMM1: S0 = relu(x @ Wi + bi) ----
        f32x4 acc[2][2];
#pragma unroll
        for (int h = 0; h < 2; h++)
#pragma unroll
            for (int b = 0; b < 2; b++)
                acc[h][b] = (f32x4){biasi[b], biasi[b], biasi[b], biasi[b]};
#pragma unroll
        for (int s = 0; s < 4; s++) {
            const half8 a0 = *(const half8*)&Ash[(ln)      * KPH + s * 32 + q * 8];
            const half8 a1 = *(const half8*)&Ash[(16 + ln) * KPH + s * 32 + q * 8];
#pragma unroll
            for (int b = 0; b < 2; b++) {
                acc[0][b] = __builtin_amdgcn_mfma_f32_16x16x32_f16(a0, WI[s][b], acc[0][b], 0, 0, 0);
                acc[1][b] = __builtin_amdgcn_mfma_f32_16x16x32_f16(a1, WI[s][b], acc[1][b], 0, 0, 0);
            }
        }
        __syncthreads();   // all A-reads of x done before overwrite

        // S0 = relu(acc): write Sh + restage to LDS
#pragma unroll
        for (int h = 0; h < 2; h++)
#pragma unroll
            for (int b = 0; b < 2; b++) {
                const int col = colBase + b * 16 + ln;
#pragma unroll
                for (int r = 0; r < 4; r++) {
                    const int lrow = h * 16 + q * 4 + r;
                    const size_t row = (size_t)tileB * 32 + lrow;
                    const _Float16 v = (_Float16)fmaxf(acc[h][b][r], 0.f);
                    Sh[row * DD + col] = v;
                    Ash[lrow * KPH + col] = v;
                }
            }
        __syncthreads();

        // ---- GEMM2: msg0 = relu(S0 @ Wm0 + bm0) ----
        f32x4 acc2[2][2];
#pragma unroll
        for (int h = 0; h < 2; h++)
#pragma unroll
            for (int b = 0; b < 2; b++)
                acc2[h][b] = (f32x4){biasm[b], biasm[b], biasm[b], biasm[b]};
#pragma unroll
        for (int s = 0; s < 4; s++) {
            const half8 a0 = *(const half8*)&Ash[(ln)      * KPH + s * 32 + q * 8];
            const half8 a1 = *(const half8*)&Ash[(16 + ln) * KPH + s * 32 + q * 8];
#pragma unroll
            for (int b = 0; b < 2; b++) {
                acc2[0][b] = __builtin_amdgcn_mfma_f32_16x16x32_f16(a0, WM[s][b], acc2[0][b], 0, 0, 0);
                acc2[1][b] = __builtin_amdgcn_mfma_f32_16x16x32_f16(a1, WM[s][b], acc2[1][b], 0, 0, 0);
            }
        }
#pragma unroll
        for (int h = 0; h < 2; h++)
#pragma unroll
            for (int b = 0; b < 2; b++) {
                const int col = colBase + b * 16 + ln;
#pragma unroll
                for (int r = 0; r < 4; r++) {
                    const size_t row = (size_t)tileB * 32 + h * 16 + q * 4 + r;
                    msg0[row * DD + col] = (_Float16)fmaxf(acc2[h][b][r], 0.f);
                }
            }
    }
}

// ---------------------------------------------------------------------------
// fused_round_k: R2's proven fused structure (gather in-kernel, masked 4-wide,
// next-tile index prefetch) + R3's verified weight DEDUP (wave owns a 32-col
// slice: WU/WM = 64 regs, was 128 duplicated) -> 3 blocks/CU (was 2).
//   Snew = Sold + relu( segment_sum(msgIn[src],dst) @ Wu + bu )
//   if WmT:  msgOut = relu( Snew @ Wm_next + bm_next )
//   else:    write fp32 Of (final round)
// ---------------------------------------------------------------------------
__global__ __launch_bounds__(256, 3) void fused_round_k(
    const _Float16* __restrict__ msgIn,
    const int* __restrict__ cursor,
    const int* __restrict__ bucket,
    const _Float16* __restrict__ WuT, const float* __restrict__ bu_r,
    const _Float16* __restrict__ WmT, const float* __restrict__ bm_r,
    const _Float16* __restrict__ Rh,
    _Float16* __restrict__ ShOut,
    _Float16* __restrict__ msgOut,
    float* __restrict__ Of)
{
    __shared__ _Float16 Ash[32 * KPH];

    const int tid  = threadIdx.x;
    const int lane = tid & 63;
    const int wave = tid >> 6;
    const int ln   = lane & 15;
    const int q    = lane >> 4;
    const int colBase = wave * 32;        // dedup: distinct 32-col slice per wave

    half8 WU[4][2], WM[4][2];
#pragma unroll
    for (int s = 0; s < 4; s++)
#pragma unroll
        for (int b = 0; b < 2; b++) {
            const size_t off = (size_t)(colBase + b * 16 + ln) * DD + s * 32 + q * 8;
            WU[s][b] = *(const half8*)&WuT[off];
            if (WmT) WM[s][b] = *(const half8*)&WmT[off];
        }
    float biasu[2], biasm[2];
#pragma unroll
    for (int b = 0; b < 2; b++) {
        biasu[b] = bu_r[colBase + b * 16 + ln];
        biasm[b] = WmT ? bm_r[colBase + b * 16 + ln] : 0.f;
    }

    const int grow = tid >> 3;     // 0..31
    const int grp  = tid & 7;      // 0..7
    const int gcol = grp * 16;

    // ---- prologue: load first tile's cnt + bucket slice ----
    int cnt = 0;
    int idxr[4];
#pragma unroll
    for (int i = 0; i < 4; i++) idxr[i] = 0;
    {
        const int node = blockIdx.x * 32 + grow;
        cnt = cursor[node];
        const int ibase = node * CAP;
#pragma unroll
        for (int i = 0; i < 4; i++) idxr[i] = bucket[ibase + grp + 8 * i];
    }

    for (int tileB = blockIdx.x; tileB < NFT; tileB += gridDim.x) {
        // ---- prefetch next tile's cnt + bucket slice (resolves under MFMAs) ----
        const int nextT = tileB + gridDim.x;
        int cntN = 0;
        int idxrN[4];
#pragma unroll
        for (int i = 0; i < 4; i++) idxrN[i] = 0;
        if (nextT < NFT) {
            const int nodeN = nextT * 32 + grow;
            cntN = cursor[nodeN];
            const int ibaseN = nodeN * CAP;
#pragma unroll
            for (int i = 0; i < 4; i++) idxrN[i] = bucket[ibaseN + grp + 8 * i];
        }

        // ---- phase 1: gather + sum, masked 4-wide (no serial tail) ----
        int c = cnt;
        if (c > CAP) c = CAP;

        float a[16];
#pragma unroll
        for (int i = 0; i < 16; i++) a[i] = 0.f;

        for (int j = 0; j < c; j += 4) {
            int ix[4];
#pragma unroll
            for (int u = 0; u < 4; u++) {
                const int jj = (j + u) & 31;           // wrap keeps idxr idx valid
                int v = __shfl(idxr[jj >> 3], (lane & 56) | (jj & 7), 64);
                ix[u] = ((unsigned)v < NN) ? v : 0;    // clamp speculative lanes
            }
            half8 v[8];
#pragma unroll
            for (int u = 0; u < 4; u++) {
                v[2 * u]     = *(const half8*)&msgIn[(size_t)ix[u] * DD + gcol];
                v[2 * u + 1] = *(const half8*)&msgIn[(size_t)ix[u] * DD + gcol + 8];
            }
#pragma unroll
            for (int u = 0; u < 4; u++) {
                if (j + u < c) {                        // exec-masked accumulate
#pragma unroll
                    for (int i = 0; i < 8; i++) {
                        a[i]     += (float)v[2 * u][i];
                        a[8 + i] += (float)v[2 * u + 1][i];
                    }
                }
            }
        }

        half8 h0, h1;
#pragma unroll
        for (int i = 0; i < 8; i++) { h0[i] = (_Float16)a[i]; h1[i] = (_Float16)a[8 + i]; }

        __syncthreads();   // prior tile's last Ash reads done
        *(half8*)&Ash[grow * KPH + gcol]     = h0;
        *(half8*)&Ash[grow * KPH + gcol + 8] = h1;
        __syncthreads();

        // ---- phase 2: agg @ Wu (residual rh prefetched to overlap MFMAs) ----
        _Float16 rh[2][2][4];
#pragma unroll
        for (int h = 0; h < 2; h++)
#pragma unroll
            for (int b = 0; b < 2; b++)
#pragma unroll
                for (int r = 0; r < 4; r++) {
                    const size_t row = (size_t)tileB * 32 + h * 16 + q * 4 + r;
                    rh[h][b][r] = Rh[row * DD + colBase + b * 16 + ln];
                }

        f32x4 acc[2][2];
#pragma unroll
        for (int h = 0; h < 2; h++)
#pragma unroll
            for (int b = 0; b < 2; b++)
                acc[h][b] = (f32x4){biasu[b], biasu[b], biasu[b], biasu[b]};
#pragma unroll
        for (int s = 0; s < 4; s++) {
            const half8 a0 = *(const half8*)&Ash[(ln)      * KPH + s * 32 + q * 8];
            const half8 a1 = *(const half8*)&Ash[(16 + ln) * KPH + s * 32 + q * 8];
#pragma unroll
            for (int b = 0; b < 2; b++) {
                acc[0][b] = __builtin_amdgcn_mfma_f32_16x16x32_f16(a0, WU[s][b], acc[0][b], 0, 0, 0);
                acc[1][b] = __builtin_amdgcn_mfma_f32_16x16x32_f16(a1, WU[s][b], acc[1][b], 0, 0, 0);
            }
        }

        if (!WmT) {
            // final round: fp32 output only
#pragma unroll
            for (int h = 0; h < 2; h++)
#pragma unroll
                for (int b = 0; b < 2; b++) {
                    const int col = colBase + b * 16 + ln;
#pragma unroll
                    for (int r = 0; r < 4; r++) {
                        const size_t row = (size_t)tileB * 32 + h * 16 + q * 4 + r;
                        Of[row * DD + col] = fmaxf(acc[h][b][r], 0.f) + (float)rh[h][b][r];
                    }
                }
            cnt = cntN;
#pragma unroll
            for (int i = 0; i < 4; i++) idxr[i] = idxrN[i];
            continue;   // loop-top barrier guards Ash reuse
        }

        __syncthreads();   // all waves done reading agg from Ash
        // Snew = Sold + relu(acc): write ShOut + restage to LDS
#pragma unroll
        for (int h = 0; h < 2; h++)
#pragma unroll
            for (int b = 0; b < 2; b++) {
                const int col = colBase + b * 16 + ln;
#pragma unroll
                for (int r = 0; r < 4; r++) {
                    const int lrow = h * 16 + q * 4 + r;
                    const size_t row = (size_t)tileB * 32 + lrow;
                    const _Float16 v =
                        (_Float16)(fmaxf(acc[h][b][r], 0.f) + (float)rh[h][b][r]);
                    ShOut[row * DD + col] = v;
                    Ash[lrow * KPH + col] = v;
                }
            }
        __syncthreads();

        // ---- phase 3: msgOut = relu(Snew @ Wm_next + bm_next) ----
        f32x4 acc2[2][2];
#pragma unroll
        for (int h = 0; h < 2; h++)
#pragma unroll
            for (int b = 0; b < 2; b++)
                acc2[h][b] = (f32x4){biasm[b], biasm[b], biasm[b], biasm[b]};
#pragma unroll
        for (int s = 0; s < 4; s++) {
            const half8 a0 = *(const half8*)&Ash[(ln)      * KPH + s * 32 + q * 8];
            const half8 a1 = *(const half8*)&Ash[(16 + ln) * KPH + s * 32 + q * 8];
#pragma unroll
            for (int b = 0; b < 2; b++) {
                acc2[0][b] = __builtin_amdgcn_mfma_f32_16x16x32_f16(a0, WM[s][b], acc2[0][b], 0, 0, 0);
                acc2[1][b] = __builtin_amdgcn_mfma_f32_16x16x32_f16(a1, WM[s][b], acc2[1][b], 0, 0, 0);
            }
        }
#pragma unroll
        for (int h = 0; h < 2; h++)
#pragma unroll
            for (int b = 0; b < 2; b++) {
                const int col = colBase + b * 16 + ln;
#pragma unroll
                for (int r = 0; r < 4; r++) {
                    const size_t row = (size_t)tileB * 32 + h * 16 + q * 4 + r;
                    msgOut[row * DD + col] = (_Float16)fmaxf(acc2[h][b][r], 0.f);
                }
            }

        cnt = cntN;
#pragma unroll
        for (int i = 0; i < 4; i++) idxr[i] = idxrN[i];
    }
}

extern "C" void kernel_launch(void* const* d_in, const int* in_sizes, int n_in,
                              void* d_out, int out_size, void* d_ws, size_t ws_size,
                              hipStream_t stream) {
    const float* x  = (const float*)d_in[0];
    const int*   ei = (const int*)d_in[1];
    const float* Wi = (const float*)d_in[2];
    const float* bi = (const float*)d_in[3];
    const float* Wm = (const float*)d_in[4];
    const float* bm = (const float*)d_in[5];
    const float* Wu = (const float*)d_in[6];
    const float* bu = (const float*)d_in[7];

    const int* src = ei;           // edge_index[0] : gather source
    const int* dst = ei + NE;      // edge_index[1] : aggregation target

    // Workspace carve (~91 MB):
    const size_t NELE = (size_t)NN * DD;
    _Float16* msgA = (_Float16*)d_ws;                    // 25.6 MB
    _Float16* msgB = msgA + NELE;                        // 25.6 MB
    _Float16* Sh   = msgB + NELE;                        // 25.6 MB
    _Float16* WT   = Sh + NELE;                          // 288 KB (9 mats)
    int* cursor = (int*)(WT + 9 * DD * DD);              // 400 KB
    int* bucket = cursor + NN;                           // 12.8 MB

    hipMemsetAsync(cursor, 0, (size_t)NN * 4, stream);
    wprep_k<<<9 * 128, 128, 0, stream>>>(Wi, Wm, Wu, WT);

    // input GEMM (+ msg0 GEMM) + bucket build (prologue), one dispatch
    prep_k<<<GEMMB, 256, 0, stream>>>(
        x, WT /*Wi*/, WT + 1 * DD * DD /*Wm0*/, bi, bm,
        Sh, msgA, src, dst, cursor, bucket);

    _Float16* mIn = msgA;
    _Float16* mOut = msgB;
    for (int r = 0; r < ROUNDS; r++) {
        const bool last = (r == ROUNDS - 1);
        fused_round_k<<<FG, 256, 0, stream>>>(
            mIn, cursor, bucket,
            WT + (size_t)(5 + r) * DD * DD, bu + (size_t)r * DD,
            last ? nullptr : WT + (size_t)(2 + r) * DD * DD,   // Wm[r+1]
            last ? nullptr : bm + (size_t)(r + 1) * DD,
            Sh, Sh, mOut,
            last ? (float*)d_out : nullptr);
        _Float16* t = mIn; mIn = mOut; mOut = t;
    }
}

// Round 5
// 377.452 us; speedup vs baseline: 1.1516x; 1.0409x over previous
//
#include <hip/hip_runtime.h>

#define NN 100000
#define NE 640000
#define DD 128
#define ROUNDS 4
#define CAP 32          // max in-degree; deg ≈ Poisson(6.4); P(any overflow) ~ 1e-9
#define NFT 3125        // NN / 32  (32-row tiles)
#define GEMMB 1024      // prep_k grid
#define FG 512          // fused grid: 2 blocks/CU x 256 CU, exactly resident
#define KPH 136         // LDS row stride in halves (272 B; 2-way bank alias free)

typedef float f32x4 __attribute__((ext_vector_type(4)));
typedef _Float16 half8 __attribute__((ext_vector_type(8)));

// ---------------------------------------------------------------------------
// Weight prep: W (128x128 fp32 [k][n]) -> WT fp16 [n][k].
// mats: 0=Wi, 1..4=Wm[0..3], 5..8=Wu[0..3].
// ---------------------------------------------------------------------------
__global__ __launch_bounds__(128) void wprep_k(
    const float* __restrict__ Wi, const float* __restrict__ Wm,
    const float* __restrict__ Wu, _Float16* __restrict__ WT)
{
    const int mat = blockIdx.x >> 7;
    const int k   = blockIdx.x & 127;
    const int n   = threadIdx.x;
    const float* W = (mat == 0) ? Wi
                   : (mat <= 4) ? Wm + (size_t)(mat - 1) * DD * DD
                                : Wu + (size_t)(mat - 5) * DD * DD;
    WT[(size_t)mat * DD * DD + (size_t)n * DD + k] = (_Float16)W[(size_t)k * DD + n];
}

// ---------------------------------------------------------------------------
// prep_k (R3 form, verified 78 us): bucket-build prologue + 32-row-tile GEMMs:
//   S0 = relu(x @ Wi + bi) -> Sh;  msg0 = relu(S0 @ Wm0 + bm0) -> msgA
// Weight dedup: each wave owns a distinct 32-col slice -> 3 blocks/CU.
// ---------------------------------------------------------------------------
__global__ __launch_bounds__(256, 3) void prep_k(
    const float* __restrict__ x,
    const _Float16* __restrict__ WiT, const _Float16* __restrict__ Wm0T,
    const float* __restrict__ bi, const float* __restrict__ bm0,
    _Float16* __restrict__ Sh, _Float16* __restrict__ msg0,
    const int* __restrict__ src, const int* __restrict__ dst,
    int* __restrict__ cursor, int* __restrict__ bucket)
{
    // ---- bucket-build prologue (all blocks) ----
    for (int e = blockIdx.x * 256 + threadIdx.x; e < NE; e += GEMMB * 256) {
        const int d = dst[e];
        const int s = src[e];
        const int pos = atomicAdd(&cursor[d], 1);
        if (pos < CAP) bucket[(long long)d * CAP + pos] = s;
    }

    __shared__ _Float16 Ash[32 * KPH];

    const int tid  = threadIdx.x;
    const int lane = tid & 63;
    const int wave = tid >> 6;
    const int ln   = lane & 15;
    const int q    = lane >> 4;
    const int colBase = wave * 32;        // dedup: distinct 32-col slice per wave

    half8 WI[4][2], WM[4][2];
#pragma unroll
    for (int s = 0; s < 4; s++)
#pragma unroll
        for (int b = 0; b < 2; b++) {
            const size_t off = (size_t)(colBase + b * 16 + ln) * DD + s * 32 + q * 8;
            WI[s][b] = *(const half8*)&WiT[off];
            WM[s][b] = *(const half8*)&Wm0T[off];
        }
    float biasi[2], biasm[2];
#pragma unroll
    for (int b = 0; b < 2; b++) {
        biasi[b] = bi[colBase + b * 16 + ln];
        biasm[b] = bm0[colBase + b * 16 + ln];
    }

    const int grow = tid >> 3;     // 0..31
    const int grp  = tid & 7;      // 0..7
    const int gcol = grp * 16;

    for (int tileB = blockIdx.x; tileB < NFT; tileB += GEMMB) {
        // ---- stage x tile -> Ash fp16 (coalesced 64 B/thread) ----
        const float* xr = x + ((size_t)tileB * 32 + grow) * DD + gcol;
        const float4 f0 = *(const float4*)&xr[0];
        const float4 f1 = *(const float4*)&xr[4];
        const float4 f2 = *(const float4*)&xr[8];
        const float4 f3 = *(const float4*)&xr[12];
        half8 hx0, hx1;
        hx0[0] = (_Float16)f0.x; hx0[1] = (_Float16)f0.y;
        hx0[2] = (_Float16)f0.z; hx0[3] = (_Float16)f0.w;
        hx0[4] = (_Float16)f1.x; hx0[5] = (_Float16)f1.y;
        hx0[6] = (_Float16)f1.z; hx0[7] = (_Float16)f1.w;
        hx1[0] = (_Float16)f2.x; hx1[1] = (_Float16)f2.y;
        hx1[2] = (_Float16)f2.z; hx1[3] = (_Float16)f2.w;
        hx1[4] = (_Float16)f3.x; hx1[5] = (_Float16)f3.y;
        hx1[6] = (_Float16)f3.z; hx1[7] = (_Float16)f3.w;

        __syncthreads();   // prior tile's phase-3 Ash reads done
        *(half8*)&Ash[grow * KPH + gcol]     = hx0;
        *(half8*)&Ash[grow * KPH + gcol + 8] = hx1;
        __syncthreads();

        // ---- GEMM1: S0 = relu(x @ Wi + bi) ----
        f32x4 acc[2][2];
#pragma unroll
        for (int h = 0; h < 2; h++)
#pragma unroll
            for (int b = 0; b < 2; b++)
                acc[h][b] = (f32x4){biasi[b], biasi[b], biasi[b], biasi[b]};
#pragma unroll
        for (int s = 0; s < 4; s++) {
            const half8 a0 = *(const half8*)&Ash[(ln)      * KPH + s * 32 + q * 8];
            const half8 a1 = *(const half8*)&Ash[(16 + ln) * KPH + s * 32 + q * 8];
#pragma unroll
            for (int b = 0; b < 2; b++) {
                acc[0][b] = __builtin_amdgcn_mfma_f32_16x16x32_f16(a0, WI[s][b], acc[0][b], 0, 0, 0);
                acc[1][b] = __builtin_amdgcn_mfma_f32_16x16x32_f16(a1, WI[s][b], acc[1][b], 0, 0, 0);
            }
        }
        __syncthreads();   // all A-reads of x done before overwrite

        // S0 = relu(acc): write Sh + restage to LDS
#pragma unroll
        for (int h = 0; h < 2; h++)
#pragma unroll
            for (int b = 0; b < 2; b++) {
                const int col = colBase + b * 16 + ln;
#pragma unroll
                for (int r = 0; r < 4; r++) {
                    const int lrow = h * 16 + q * 4 + r;
                    const size_t row = (size_t)tileB * 32 + lrow;
                    const _Float16 v = (_Float16)fmaxf(acc[h][b][r], 0.f);
                    Sh[row * DD + col] = v;
                    Ash[lrow * KPH + col] = v;
                }
            }
        __syncthreads();

        // ---- GEMM2: msg0 = relu(S0 @ Wm0 + bm0) ----
        f32x4 acc2[2][2];
#pragma unroll
        for (int h = 0; h < 2; h++)
#pragma unroll
            for (int b = 0; b < 2; b++)
                acc2[h][b] = (f32x4){biasm[b], biasm[b], biasm[b], biasm[b]};
#pragma unroll
        for (int s = 0; s < 4; s++) {
            const half8 a0 = *(const half8*)&Ash[(ln)      * KPH + s * 32 + q * 8];
            const half8 a1 = *(const half8*)&Ash[(16 + ln) * KPH + s * 32 + q * 8];
#pragma unroll
            for (int b = 0; b < 2; b++) {
                acc2[0][b] = __builtin_amdgcn_mfma_f32_16x16x32_f16(a0, WM[s][b], acc2[0][b], 0, 0, 0);
                acc2[1][b] = __builtin_amdgcn_mfma_f32_16x16x32_f16(a1, WM[s][b], acc2[1][b], 0, 0, 0);
            }
        }
#pragma unroll
        for (int h = 0; h < 2; h++)
#pragma unroll
            for (int b = 0; b < 2; b++) {
                const int col = colBase + b * 16 + ln;
#pragma unroll
                for (int r = 0; r < 4; r++) {
                    const size_t row = (size_t)tileB * 32 + h * 16 + q * 4 + r;
                    msg0[row * DD + col] = (_Float16)fmaxf(acc2[h][b][r], 0.f);
                }
            }
    }
}

// ---------------------------------------------------------------------------
// fused_round_k: R2's proven fused structure, weight dedup kept (frees 64
// regs), but __launch_bounds__(256,2) restores the 256-reg budget — the freed
// registers are SPENT on an 8-wide gather (16 loads in flight/lane, 128/CU;
// R4's (256,3) cap made the allocator serialize the loads: VGPR fell to 84
// and the round got 13 us slower).
//   Snew = Sold + relu( segment_sum(msgIn[src],dst) @ Wu + bu )
//   if WmT:  msgOut = relu( Snew @ Wm_next + bm_next )
//   else:    write fp32 Of (final round)
// ---------------------------------------------------------------------------
__global__ __launch_bounds__(256, 2) void fused_round_k(
    const _Float16* __restrict__ msgIn,
    const int* __restrict__ cursor,
    const int* __restrict__ bucket,
    const _Float16* __restrict__ WuT, const float* __restrict__ bu_r,
    const _Float16* __restrict__ WmT, const float* __restrict__ bm_r,
    const _Float16* __restrict__ Rh,
    _Float16* __restrict__ ShOut,
    _Float16* __restrict__ msgOut,
    float* __restrict__ Of)
{
    __shared__ _Float16 Ash[32 * KPH];

    const int tid  = threadIdx.x;
    const int lane = tid & 63;
    const int wave = tid >> 6;
    const int ln   = lane & 15;
    const int q    = lane >> 4;
    const int colBase = wave * 32;        // dedup: distinct 32-col slice per wave

    half8 WU[4][2], WM[4][2];
#pragma unroll
    for (int s = 0; s < 4; s++)
#pragma unroll
        for (int b = 0; b < 2; b++) {
            const size_t off = (size_t)(colBase + b * 16 + ln) * DD + s * 32 + q * 8;
            WU[s][b] = *(const half8*)&WuT[off];
            if (WmT) WM[s][b] = *(const half8*)&WmT[off];
        }
    float biasu[2], biasm[2];
#pragma unroll
    for (int b = 0; b < 2; b++) {
        biasu[b] = bu_r[colBase + b * 16 + ln];
        biasm[b] = WmT ? bm_r[colBase + b * 16 + ln] : 0.f;
    }

    const int grow = tid >> 3;     // 0..31
    const int grp  = tid & 7;      // 0..7
    const int gcol = grp * 16;

    // ---- prologue: load first tile's cnt + bucket slice ----
    int cnt = 0;
    int idxr[4];
#pragma unroll
    for (int i = 0; i < 4; i++) idxr[i] = 0;
    {
        const int node = blockIdx.x * 32 + grow;
        cnt = cursor[node];
        const int ibase = node * CAP;
#pragma unroll
        for (int i = 0; i < 4; i++) idxr[i] = bucket[ibase + grp + 8 * i];
    }

    for (int tileB = blockIdx.x; tileB < NFT; tileB += gridDim.x) {
        // ---- prefetch next tile's cnt + bucket slice (resolves under MFMAs) ----
        const int nextT = tileB + gridDim.x;
        int cntN = 0;
        int idxrN[4];
#pragma unroll
        for (int i = 0; i < 4; i++) idxrN[i] = 0;
        if (nextT < NFT) {
            const int nodeN = nextT * 32 + grow;
            cntN = cursor[nodeN];
            const int ibaseN = nodeN * CAP;
#pragma unroll
            for (int i = 0; i < 4; i++) idxrN[i] = bucket[ibaseN + grp + 8 * i];
        }

        // ---- phase 1: gather + sum, masked 8-WIDE (16 loads in flight) ----
        int c = cnt;
        if (c > CAP) c = CAP;

        float a[16];
#pragma unroll
        for (int i = 0; i < 16; i++) a[i] = 0.f;

        for (int j = 0; j < c; j += 8) {
            int ix[8];
#pragma unroll
            for (int u = 0; u < 8; u++) {
                const int jj = (j + u) & 31;           // wrap keeps idxr idx valid
                int v = __shfl(idxr[jj >> 3], (lane & 56) | (jj & 7), 64);
                ix[u] = ((unsigned)v < NN) ? v : 0;    // clamp speculative lanes
            }
            half8 v[16];
#pragma unroll
            for (int u = 0; u < 8; u++) {
                v[2 * u]     = *(const half8*)&msgIn[(size_t)ix[u] * DD + gcol];
                v[2 * u + 1] = *(const half8*)&msgIn[(size_t)ix[u] * DD + gcol + 8];
            }
#pragma unroll
            for (int u = 0; u < 8; u++) {
                if (j + u < c) {                        // exec-masked accumulate
#pragma unroll
                    for (int i = 0; i < 8; i++) {
                        a[i]     += (float)v[2 * u][i];
                        a[8 + i] += (float)v[2 * u + 1][i];
                    }
                }
            }
        }

        half8 h0, h1;
#pragma unroll
        for (int i = 0; i < 8; i++) { h0[i] = (_Float16)a[i]; h1[i] = (_Float16)a[8 + i]; }

        __syncthreads();   // prior tile's last Ash reads done
        *(half8*)&Ash[grow * KPH + gcol]     = h0;
        *(half8*)&Ash[grow * KPH + gcol + 8] = h1;
        __syncthreads();

        // ---- phase 2: agg @ Wu (residual rh prefetched to overlap MFMAs) ----
        _Float16 rh[2][2][4];
#pragma unroll
        for (int h = 0; h < 2; h++)
#pragma unroll
            for (int b = 0; b < 2; b++)
#pragma unroll
                for (int r = 0; r < 4; r++) {
                    const size_t row = (size_t)tileB * 32 + h * 16 + q * 4 + r;
                    rh[h][b][r] = Rh[row * DD + colBase + b * 16 + ln];
                }

        f32x4 acc[2][2];
#pragma unroll
        for (int h = 0; h < 2; h++)
#pragma unroll
            for (int b = 0; b < 2; b++)
                acc[h][b] = (f32x4){biasu[b], biasu[b], biasu[b], biasu[b]};
#pragma unroll
        for (int s = 0; s < 4; s++) {
            const half8 a0 = *(const half8*)&Ash[(ln)      * KPH + s * 32 + q * 8];
            const half8 a1 = *(const half8*)&Ash[(16 + ln) * KPH + s * 32 + q * 8];
#pragma unroll
            for (int b = 0; b < 2; b++) {
                acc[0][b] = __builtin_amdgcn_mfma_f32_16x16x32_f16(a0, WU[s][b], acc[0][b], 0, 0, 0);
                acc[1][b] = __builtin_amdgcn_mfma_f32_16x16x32_f16(a1, WU[s][b], acc[1][b], 0, 0, 0);
            }
        }

        if (!WmT) {
            // final round: fp32 output only
#pragma unroll
            for (int h = 0; h < 2; h++)
#pragma unroll
                for (int b = 0; b < 2; b++) {
                    const int col = colBase + b * 16 + ln;
#pragma unroll
                    for (int r = 0; r < 4; r++) {
                        const size_t row = (size_t)tileB * 32 + h * 16 + q * 4 + r;
                        Of[row * DD + col] = fmaxf(acc[h][b][r], 0.f) + (float)rh[h][b][r];
                    }
                }
            cnt = cntN;
#pragma unroll
            for (int i = 0; i < 4; i++) idxr[i] = idxrN[i];
            continue;   // loop-top barrier guards Ash reuse
        }

        __syncthreads();   // all waves done reading agg from Ash
        // Snew = Sold + relu(acc): write ShOut + restage to LDS
#pragma unroll
        for (int h = 0; h < 2; h++)
#pragma unroll
            for (int b = 0; b < 2; b++) {
                const int col = colBase + b * 16 + ln;
#pragma unroll
                for (int r = 0; r < 4; r++) {
                    const int lrow = h * 16 + q * 4 + r;
                    const size_t row = (size_t)tileB * 32 + lrow;
                    const _Float16 v =
                        (_Float16)(fmaxf(acc[h][b][r], 0.f) + (float)rh[h][b][r]);
                    ShOut[row * DD + col] = v;
                    Ash[lrow * KPH + col] = v;
                }
            }
        __syncthreads();

        // ---- phase 3: msgOut = relu(Snew @ Wm_next + bm_next) ----
        f32x4 acc2[2][2];
#pragma unroll
        for (int h = 0; h < 2; h++)
#pragma unroll
            for (int b = 0; b < 2; b++)
                acc2[h][b] = (f32x4){biasm[b], biasm[b], biasm[b], biasm[b]};
#pragma unroll
        for (int s = 0; s < 4; s++) {
            const half8 a0 = *(const half8*)&Ash[(ln)      * KPH + s * 32 + q * 8];
            const half8 a1 = *(const half8*)&Ash[(16 + ln) * KPH + s * 32 + q * 8];
#pragma unroll
            for (int b = 0; b < 2; b++) {
                acc2[0][b] = __builtin_amdgcn_mfma_f32_16x16x32_f16(a0, WM[s][b], acc2[0][b], 0, 0, 0);
                acc2[1][b] = __builtin_amdgcn_mfma_f32_16x16x32_f16(a1, WM[s][b], acc2[1][b], 0, 0, 0);
            }
        }
#pragma unroll
        for (int h = 0; h < 2; h++)
#pragma unroll
            for (int b = 0; b < 2; b++) {
                const int col = colBase + b * 16 + ln;
#pragma unroll
                for (int r = 0; r < 4; r++) {
                    const size_t row = (size_t)tileB * 32 + h * 16 + q * 4 + r;
                    msgOut[row * DD + col] = (_Float16)fmaxf(acc2[h][b][r], 0.f);
                }
            }

        cnt = cntN;
#pragma unroll
        for (int i = 0; i < 4; i++) idxr[i] = idxrN[i];
    }
}

extern "C" void kernel_launch(void* const* d_in, const int* in_sizes, int n_in,
                              void* d_out, int out_size, void* d_ws, size_t ws_size,
                              hipStream_t stream) {
    const float* x  = (const float*)d_in[0];
    const int*   ei = (const int*)d_in[1];
    const float* Wi = (const float*)d_in[2];
    const float* bi = (const float*)d_in[3];
    const float* Wm = (const float*)d_in[4];
    const float* bm = (const float*)d_in[5];
    const float* Wu = (const float*)d_in[6];
    const float* bu = (const float*)d_in[7];

    const int* src = ei;           // edge_index[0] : gather source
    const int* dst = ei + NE;      // edge_index[1] : aggregation target

    // Workspace carve (~91 MB):
    const size_t NELE = (size_t)NN * DD;
    _Float16* msgA = (_Float16*)d_ws;                    // 25.6 MB
    _Float16* msgB = msgA + NELE;                        // 25.6 MB
    _Float16* Sh   = msgB + NELE;                        // 25.6 MB
    _Float16* WT   = Sh + NELE;                          // 288 KB (9 mats)
    int* cursor = (int*)(WT + 9 * DD * DD);              // 400 KB
    int* bucket = cursor + NN;                           // 12.8 MB

    hipMemsetAsync(cursor, 0, (size_t)NN * 4, stream);
    wprep_k<<<9 * 128, 128, 0, stream>>>(Wi, Wm, Wu, WT);

    // input GEMM (+ msg0 GEMM) + bucket build (prologue), one dispatch
    prep_k<<<GEMMB, 256, 0, stream>>>(
        x, WT /*Wi*/, WT + 1 * DD * DD /*Wm0*/, bi, bm,
        Sh, msgA, src, dst, cursor, bucket);

    _Float16* mIn = msgA;
    _Float16* mOut = msgB;
    for (int r = 0; r < ROUNDS; r++) {
        const bool last = (r == ROUNDS - 1);
        fused_round_k<<<FG, 256, 0, stream>>>(
            mIn, cursor, bucket,
            WT + (size_t)(5 + r) * DD * DD, bu + (size_t)r * DD,
            last ? nullptr : WT + (size_t)(2 + r) * DD * DD,   // Wm[r+1]
            last ? nullptr : bm + (size_t)(r + 1) * DD,
            Sh, Sh, mOut,
            last ? (float*)d_out : nullptr);
        _Float16* t = mIn; mIn = mOut; mOut = t;
    }
}

// Round 6
// 355.941 us; speedup vs baseline: 1.2212x; 1.0604x over previous
//
#include <hip/hip_runtime.h>

#define NN 100000
#define NE 640000
#define DD 128
#define ROUNDS 4
#define CAP 32          // max in-degree; deg ≈ Poisson(6.4); P(any overflow) ~ 1e-9
#define NFT 3125        // NN / 32  (32-row tiles)
#define GEMMB 1024      // prep_k grid
#define FG 512          // fused grid: 2 blocks/CU x 256 CU, exactly resident
#define KPH 136         // LDS row stride in halves (272 B; 2-way bank alias free)

typedef float f32x4 __attribute__((ext_vector_type(4)));
typedef _Float16 half8 __attribute__((ext_vector_type(8)));

// ---------------------------------------------------------------------------
// Weight prep: W (128x128 fp32 [k][n]) -> WT fp16 [n][k].
// mats: 0=Wi, 1..4=Wm[0..3], 5..8=Wu[0..3].
// ---------------------------------------------------------------------------
__global__ __launch_bounds__(128) void wprep_k(
    const float* __restrict__ Wi, const float* __restrict__ Wm,
    const float* __restrict__ Wu, _Float16* __restrict__ WT)
{
    const int mat = blockIdx.x >> 7;
    const int k   = blockIdx.x & 127;
    const int n   = threadIdx.x;
    const float* W = (mat == 0) ? Wi
                   : (mat <= 4) ? Wm + (size_t)(mat - 1) * DD * DD
                                : Wu + (size_t)(mat - 5) * DD * DD;
    WT[(size_t)mat * DD * DD + (size_t)n * DD + k] = (_Float16)W[(size_t)k * DD + n];
}

// ---------------------------------------------------------------------------
// prep_k (R5 form, verified 78-81 us): bucket-build prologue + 32-row GEMMs:
//   S0 = relu(x @ Wi + bi) -> Sh;  msg0 = relu(S0 @ Wm0 + bm0) -> msgA
// Weight dedup (wave owns a 32-col slice) + coalesced x staging -> 3 blk/CU.
// ---------------------------------------------------------------------------
__global__ __launch_bounds__(256, 3) void prep_k(
    const float* __restrict__ x,
    const _Float16* __restrict__ WiT, const _Float16* __restrict__ Wm0T,
    const float* __restrict__ bi, const float* __restrict__ bm0,
    _Float16* __restrict__ Sh, _Float16* __restrict__ msg0,
    const int* __restrict__ src, const int* __restrict__ dst,
    int* __restrict__ cursor, int* __restrict__ bucket)
{
    // ---- bucket-build prologue (all blocks) ----
    for (int e = blockIdx.x * 256 + threadIdx.x; e < NE; e += GEMMB * 256) {
        const int d = dst[e];
        const int s = src[e];
        const int pos = atomicAdd(&cursor[d], 1);
        if (pos < CAP) bucket[(long long)d * CAP + pos] = s;
    }

    __shared__ _Float16 Ash[32 * KPH];

    const int tid  = threadIdx.x;
    const int lane = tid & 63;
    const int wave = tid >> 6;
    const int ln   = lane & 15;
    const int q    = lane >> 4;
    const int colBase = wave * 32;        // dedup: distinct 32-col slice per wave

    half8 WI[4][2], WM[4][2];
#pragma unroll
    for (int s = 0; s < 4; s++)
#pragma unroll
        for (int b = 0; b < 2; b++) {
            const size_t off = (size_t)(colBase + b * 16 + ln) * DD + s * 32 + q * 8;
            WI[s][b] = *(const half8*)&WiT[off];
            WM[s][b] = *(const half8*)&Wm0T[off];
        }
    float biasi[2], biasm[2];
#pragma unroll
    for (int b = 0; b < 2; b++) {
        biasi[b] = bi[colBase + b * 16 + ln];
        biasm[b] = bm0[colBase + b * 16 + ln];
    }

    const int grow = tid >> 3;     // 0..31
    const int grp  = tid & 7;      // 0..7
    const int gcol = grp * 16;

    for (int tileB = blockIdx.x; tileB < NFT; tileB += GEMMB) {
        // ---- stage x tile -> Ash fp16 (coalesced 64 B/thread) ----
        const float* xr = x + ((size_t)tileB * 32 + grow) * DD + gcol;
        const float4 f0 = *(const float4*)&xr[0];
        const float4 f1 = *(const float4*)&xr[4];
        const float4 f2 = *(const float4*)&xr[8];
        const float4 f3 = *(const float4*)&xr[12];
        half8 hx0, hx1;
        hx0[0] = (_Float16)f0.x; hx0[1] = (_Float16)f0.y;
        hx0[2] = (_Float16)f0.z; hx0[3] = (_Float16)f0.w;
        hx0[4] = (_Float16)f1.x; hx0[5] = (_Float16)f1.y;
        hx0[6] = (_Float16)f1.z; hx0[7] = (_Float16)f1.w;
        hx1[0] = (_Float16)f2.x; hx1[1] = (_Float16)f2.y;
        hx1[2] = (_Float16)f2.z; hx1[3] = (_Float16)f2.w;
        hx1[4] = (_Float16)f3.x; hx1[5] = (_Float16)f3.y;
        hx1[6] = (_Float16)f3.z; hx1[7] = (_Float16)f3.w;

        __syncthreads();   // prior tile's phase-3 Ash reads done
        *(half8*)&Ash[grow * KPH + gcol]     = hx0;
        *(half8*)&Ash[grow * KPH + gcol + 8] = hx1;
        __syncthreads();

        // ---- GEMM1: S0 = relu(x @ Wi + bi) ----
        f32x4 acc[2][2];
#pragma unroll
        for (int h = 0; h < 2; h++)
#pragma unroll
            for (int b = 0; b < 2; b++)
                acc[h][b] = (f32x4){biasi[b], biasi[b], biasi[b], biasi[b]};
#pragma unroll
        for (int s = 0; s < 4; s++) {
            const half8 a0 = *(const half8*)&Ash[(ln)      * KPH + s * 32 + q * 8];
            const half8 a1 = *(const half8*)&Ash[(16 + ln) * KPH + s * 32 + q * 8];
#pragma unroll
            for (int b = 0; b < 2; b++) {
                acc[0][b] = __builtin_amdgcn_mfma_f32_16x16x32_f16(a0, WI[s][b], acc[0][b], 0, 0, 0);
                acc[1][b] = __builtin_amdgcn_mfma_f32_16x16x32_f16(a1, WI[s][b], acc[1][b], 0, 0, 0);
            }
        }
        __syncthreads();   // all A-reads of x done before overwrite

        // S0 = relu(acc): write Sh + restage to LDS
#pragma unroll
        for (int h = 0; h < 2; h++)
#pragma unroll
            for (int b = 0; b < 2; b++) {
                const int col = colBase + b * 16 + ln;
#pragma unroll
                for (int r = 0; r < 4; r++) {
                    const int lrow = h * 16 + q * 4 + r;
                    const size_t row = (size_t)tileB * 32 + lrow;
                    const _Float16 v = (_Float16)fmaxf(acc[h][b][r], 0.f);
                    Sh[row * DD + col] = v;
                    Ash[lrow * KPH + col] = v;
                }
            }
        __syncthreads();

        // ---- GEMM2: msg0 = relu(S0 @ Wm0 + bm0) ----
        f32x4 acc2[2][2];
#pragma unroll
        for (int h = 0; h < 2; h++)
#pragma unroll
            for (int b = 0; b < 2; b++)
                acc2[h][b] = (f32x4){biasm[b], biasm[b], biasm[b], biasm[b]};
#pragma unroll
        for (int s = 0; s < 4; s++) {
            const half8 a0 = *(const half8*)&Ash[(ln)      * KPH + s * 32 + q * 8];
            const half8 a1 = *(const half8*)&Ash[(16 + ln) * KPH + s * 32 + q * 8];
#pragma unroll
            for (int b = 0; b < 2; b++) {
                acc2[0][b] = __builtin_amdgcn_mfma_f32_16x16x32_f16(a0, WM[s][b], acc2[0][b], 0, 0, 0);
                acc2[1][b] = __builtin_amdgcn_mfma_f32_16x16x32_f16(a1, WM[s][b], acc2[1][b], 0, 0, 0);
            }
        }
#pragma unroll
        for (int h = 0; h < 2; h++)
#pragma unroll
            for (int b = 0; b < 2; b++) {
                const int col = colBase + b * 16 + ln;
#pragma unroll
                for (int r = 0; r < 4; r++) {
                    const size_t row = (size_t)tileB * 32 + h * 16 + q * 4 + r;
                    msg0[row * DD + col] = (_Float16)fmaxf(acc2[h][b][r], 0.f);
                }
            }
    }
}

// ---------------------------------------------------------------------------
// fused_round_k: EXACT R2 form (best measured: ~63-65 us/round, total 348).
// Duplicated weights (wave pair shares a 64-col slice), masked 4-wide gather,
// next-tile index prefetch, (256,2). Bucket is now ZERO-INITIALIZED by the
// host, so speculative gather lanes past cnt hit row 0 (broadcast, cache-hot)
// instead of garbage-addressed random rows.
//   Snew = Sold + relu( segment_sum(msgIn[src],dst) @ Wu + bu )
//   if WmT:  msgOut = relu( Snew @ Wm_next + bm_next )
//   else:    write fp32 Of (final round)
// ---------------------------------------------------------------------------
__global__ __launch_bounds__(256, 2) void fused_round_k(
    const _Float16* __restrict__ msgIn,
    const int* __restrict__ cursor,
    const int* __restrict__ bucket,
    const _Float16* __restrict__ WuT, const float* __restrict__ bu_r,
    const _Float16* __restrict__ WmT, const float* __restrict__ bm_r,
    const _Float16* __restrict__ Rh,
    _Float16* __restrict__ ShOut,
    _Float16* __restrict__ msgOut,
    float* __restrict__ Of)
{
    __shared__ _Float16 Ash[32 * KPH];

    const int tid  = threadIdx.x;
    const int lane = tid & 63;
    const int wave = tid >> 6;
    const int ln   = lane & 15;
    const int q    = lane >> 4;
    const int st   = (wave & 1) * 16;
    const int colBase = (wave >> 1) * 64;

    half8 WU[4][4], WM[4][4];
#pragma unroll
    for (int s = 0; s < 4; s++) {
#pragma unroll
        for (int b = 0; b < 4; b++) {
            const size_t off = (size_t)(colBase + b * 16 + ln) * DD + s * 32 + q * 8;
            WU[s][b] = *(const half8*)&WuT[off];
            if (WmT) WM[s][b] = *(const half8*)&WmT[off];
        }
    }
    float biasu[4], biasm[4];
#pragma unroll
    for (int b = 0; b < 4; b++) {
        biasu[b] = bu_r[colBase + b * 16 + ln];
        biasm[b] = WmT ? bm_r[colBase + b * 16 + ln] : 0.f;
    }

    const int grow = tid >> 3;     // 0..31
    const int grp  = tid & 7;      // 0..7
    const int gcol = grp * 16;

    // ---- prologue: load first tile's cnt + bucket slice ----
    int cnt = 0;
    int idxr[4];
#pragma unroll
    for (int i = 0; i < 4; i++) idxr[i] = 0;
    {
        const int node = blockIdx.x * 32 + grow;
        cnt = cursor[node];
        const int ibase = node * CAP;
#pragma unroll
        for (int i = 0; i < 4; i++) idxr[i] = bucket[ibase + grp + 8 * i];
    }

    for (int tileB = blockIdx.x; tileB < NFT; tileB += gridDim.x) {
        // ---- prefetch next tile's cnt + bucket slice (resolves under MFMAs) ----
        const int nextT = tileB + gridDim.x;
        int cntN = 0;
        int idxrN[4];
#pragma unroll
        for (int i = 0; i < 4; i++) idxrN[i] = 0;
        if (nextT < NFT) {
            const int nodeN = nextT * 32 + grow;
            cntN = cursor[nodeN];
            const int ibaseN = nodeN * CAP;
#pragma unroll
            for (int i = 0; i < 4; i++) idxrN[i] = bucket[ibaseN + grp + 8 * i];
        }

        // ---- phase 1: gather + sum, masked 4-wide (no serial tail) ----
        int c = cnt;
        if (c > CAP) c = CAP;

        float a[16];
#pragma unroll
        for (int i = 0; i < 16; i++) a[i] = 0.f;

        for (int j = 0; j < c; j += 4) {
            int ix[4];
#pragma unroll
            for (int u = 0; u < 4; u++) {
                const int jj = (j + u) & 31;           // wrap keeps idxr idx valid
                int v = __shfl(idxr[jj >> 3], (lane & 56) | (jj & 7), 64);
                ix[u] = ((unsigned)v < NN) ? v : 0;    // clamp speculative lanes
            }
            half8 v[8];
#pragma unroll
            for (int u = 0; u < 4; u++) {
                v[2 * u]     = *(const half8*)&msgIn[(size_t)ix[u] * DD + gcol];
                v[2 * u + 1] = *(const half8*)&msgIn[(size_t)ix[u] * DD + gcol + 8];
            }
#pragma unroll
            for (int u = 0; u < 4; u++) {
                if (j + u < c) {                        // exec-masked accumulate
#pragma unroll
                    for (int i = 0; i < 8; i++) {
                        a[i]     += (float)v[2 * u][i];
                        a[8 + i] += (float)v[2 * u + 1][i];
                    }
                }
            }
        }

        half8 h0, h1;
#pragma unroll
        for (int i = 0; i < 8; i++) { h0[i] = (_Float16)a[i]; h1[i] = (_Float16)a[8 + i]; }

        __syncthreads();   // prior tile's last Ash reads done
        *(half8*)&Ash[grow * KPH + gcol]     = h0;
        *(half8*)&Ash[grow * KPH + gcol + 8] = h1;
        __syncthreads();

        // ---- phase 2: agg @ Wu (residual rh prefetched to overlap MFMAs) ----
        _Float16 rh[4][4];
#pragma unroll
        for (int b = 0; b < 4; b++)
#pragma unroll
            for (int r = 0; r < 4; r++) {
                const size_t row = (size_t)tileB * 32 + st + q * 4 + r;
                rh[b][r] = Rh[row * DD + colBase + b * 16 + ln];
            }

        f32x4 acc[4];
#pragma unroll
        for (int b = 0; b < 4; b++)
            acc[b] = (f32x4){biasu[b], biasu[b], biasu[b], biasu[b]};
#pragma unroll
        for (int s = 0; s < 4; s++) {
            const half8 aH = *(const half8*)&Ash[(st + ln) * KPH + s * 32 + q * 8];
#pragma unroll
            for (int b = 0; b < 4; b++)
                acc[b] = __builtin_amdgcn_mfma_f32_16x16x32_f16(aH, WU[s][b], acc[b], 0, 0, 0);
        }

        if (!WmT) {
            // final round: fp32 output only
#pragma unroll
            for (int b = 0; b < 4; b++) {
                const int col = colBase + b * 16 + ln;
#pragma unroll
                for (int r = 0; r < 4; r++) {
                    const size_t row = (size_t)tileB * 32 + st + q * 4 + r;
                    Of[row * DD + col] = fmaxf(acc[b][r], 0.f) + (float)rh[b][r];
                }
            }
            cnt = cntN;
#pragma unroll
            for (int i = 0; i < 4; i++) idxr[i] = idxrN[i];
            continue;   // loop-top barrier guards Ash reuse
        }

        __syncthreads();   // all waves done reading agg from Ash
        // Snew = Sold + relu(acc): write ShOut + restage to LDS
#pragma unroll
        for (int b = 0; b < 4; b++) {
            const int col = colBase + b * 16 + ln;
#pragma unroll
            for (int r = 0; r < 4; r++) {
                const size_t row = (size_t)tileB * 32 + st + q * 4 + r;
                const _Float16 v = (_Float16)(fmaxf(acc[b][r], 0.f) + (float)rh[b][r]);
                ShOut[row * DD + col] = v;
                Ash[(st + q * 4 + r) * KPH + col] = v;
            }
        }
        __syncthreads();

        // ---- phase 3: msgOut = relu(Snew @ Wm_next + bm_next) ----
        f32x4 acc2[4];
#pragma unroll
        for (int b = 0; b < 4; b++)
            acc2[b] = (f32x4){biasm[b], biasm[b], biasm[b], biasm[b]};
#pragma unroll
        for (int s = 0; s < 4; s++) {
            const half8 aS = *(const half8*)&Ash[(st + ln) * KPH + s * 32 + q * 8];
#pragma unroll
            for (int b = 0; b < 4; b++)
                acc2[b] = __builtin_amdgcn_mfma_f32_16x16x32_f16(aS, WM[s][b], acc2[b], 0, 0, 0);
        }
#pragma unroll
        for (int b = 0; b < 4; b++) {
            const int col = colBase + b * 16 + ln;
#pragma unroll
            for (int r = 0; r < 4; r++) {
                const size_t row = (size_t)tileB * 32 + st + q * 4 + r;
                msgOut[row * DD + col] = (_Float16)fmaxf(acc2[b][r], 0.f);
            }
        }

        cnt = cntN;
#pragma unroll
        for (int i = 0; i < 4; i++) idxr[i] = idxrN[i];
    }
}

extern "C" void kernel_launch(void* const* d_in, const int* in_sizes, int n_in,
                              void* d_out, int out_size, void* d_ws, size_t ws_size,
                              hipStream_t stream) {
    const float* x  = (const float*)d_in[0];
    const int*   ei = (const int*)d_in[1];
    const float* Wi = (const float*)d_in[2];
    const float* bi = (const float*)d_in[3];
    const float* Wm = (const float*)d_in[4];
    const float* bm = (const float*)d_in[5];
    const float* Wu = (const float*)d_in[6];
    const float* bu = (const float*)d_in[7];

    const int* src = ei;           // edge_index[0] : gather source
    const int* dst = ei + NE;      // edge_index[1] : aggregation target

    // Workspace carve (~91 MB):
    const size_t NELE = (size_t)NN * DD;
    _Float16* msgA = (_Float16*)d_ws;                    // 25.6 MB
    _Float16* msgB = msgA + NELE;                        // 25.6 MB
    _Float16* Sh   = msgB + NELE;                        // 25.6 MB
    _Float16* WT   = Sh + NELE;                          // 288 KB (9 mats)
    int* cursor = (int*)(WT + 9 * DD * DD);              // 400 KB
    int* bucket = cursor + NN;                           // 12.8 MB

    hipMemsetAsync(cursor, 0, (size_t)NN * 4, stream);
    // Zero bucket so speculative gather lanes (past cnt) read row 0
    // (broadcast, cache-hot) instead of garbage-addressed random rows.
    hipMemsetAsync(bucket, 0, (size_t)NN * CAP * 4, stream);
    wprep_k<<<9 * 128, 128, 0, stream>>>(Wi, Wm, Wu, WT);

    // input GEMM (+ msg0 GEMM) + bucket build (prologue), one dispatch
    prep_k<<<GEMMB, 256, 0, stream>>>(
        x, WT /*Wi*/, WT + 1 * DD * DD /*Wm0*/, bi, bm,
        Sh, msgA, src, dst, cursor, bucket);

    _Float16* mIn = msgA;
    _Float16* mOut = msgB;
    for (int r = 0; r < ROUNDS; r++) {
        const bool last = (r == ROUNDS - 1);
        fused_round_k<<<FG, 256, 0, stream>>>(
            mIn, cursor, bucket,
            WT + (size_t)(5 + r) * DD * DD, bu + (size_t)r * DD,
            last ? nullptr : WT + (size_t)(2 + r) * DD * DD,   // Wm[r+1]
            last ? nullptr : bm + (size_t)(r + 1) * DD,
            Sh, Sh, mOut,
            last ? (float*)d_out : nullptr);
        _Float16* t = mIn; mIn = mOut; mOut = t;
    }
}

// Round 7
// 339.377 us; speedup vs baseline: 1.2808x; 1.0488x over previous
//
#include <hip/hip_runtime.h>

#define NN 100000
#define NE 640000
#define DD 128
#define ROUNDS 4
#define CAP 32          // max in-degree; deg ≈ Poisson(6.4); P(any overflow) ~ 1e-9
#define NFT 3125        // NN / 32  (32-row tiles)
#define PREPB 768       // prep_k grid: 3 blocks/CU x 256 CU, exactly resident
#define BUILDB 256      // blocks [0,BUILDB): bucket build; [BUILDB,PREPB): GEMM
#define FG 512          // fused grid: 2 blocks/CU x 256 CU, exactly resident
#define KPH 136         // LDS row stride in halves (272 B; 2-way bank alias free)

typedef float f32x4 __attribute__((ext_vector_type(4)));
typedef _Float16 half8 __attribute__((ext_vector_type(8)));

// ---------------------------------------------------------------------------
// Weight prep: W (128x128 fp32 [k][n]) -> WT fp16 [n][k].
// mats: 0=Wi, 1..4=Wm[0..3], 5..8=Wu[0..3].
// ---------------------------------------------------------------------------
__global__ __launch_bounds__(128) void wprep_k(
    const float* __restrict__ Wi, const float* __restrict__ Wm,
    const float* __restrict__ Wu, _Float16* __restrict__ WT)
{
    const int mat = blockIdx.x >> 7;
    const int k   = blockIdx.x & 127;
    const int n   = threadIdx.x;
    const float* W = (mat == 0) ? Wi
                   : (mat <= 4) ? Wm + (size_t)(mat - 1) * DD * DD
                                : Wu + (size_t)(mat - 5) * DD * DD;
    WT[(size_t)mat * DD * DD + (size_t)n * DD + k] = (_Float16)W[(size_t)k * DD + n];
}

// ---------------------------------------------------------------------------
// prep_k: CONCURRENT build || GEMM via disjoint block ranges, all resident.
//   blocks [0,BUILDB):       bucket build (1 atomic/edge) — nothing else.
//   blocks [BUILDB,PREPB):   32-row-tile GEMM chain:
//       S0 = relu(x @ Wi + bi) -> Sh;  msg0 = relu(S0 @ Wm0 + bm0) -> msgA
// Rationale: build needs no ordering vs GEMM (bucket first consumed by
// fused_round_k, fenced by stream order). Previous form ran build as a
// prologue in EVERY block -> whole GPU serialized ~30-40 us of atomics
// before any GEMM. R0's split failed only because its 1024-block grid
// exceeded the 512 residency slots; 768 = exact 3/CU residency.
// GEMM part is R5's verified form (weight dedup, coalesced x staging).
// ---------------------------------------------------------------------------
__global__ __launch_bounds__(256, 3) void prep_k(
    const float* __restrict__ x,
    const _Float16* __restrict__ WiT, const _Float16* __restrict__ Wm0T,
    const float* __restrict__ bi, const float* __restrict__ bm0,
    _Float16* __restrict__ Sh, _Float16* __restrict__ msg0,
    const int* __restrict__ src, const int* __restrict__ dst,
    int* __restrict__ cursor, int* __restrict__ bucket)
{
    if (blockIdx.x < BUILDB) {
        // ---- build-only blocks ----
        for (int e = blockIdx.x * 256 + threadIdx.x; e < NE; e += BUILDB * 256) {
            const int d = dst[e];
            const int s = src[e];
            const int pos = atomicAdd(&cursor[d], 1);
            if (pos < CAP) bucket[(long long)d * CAP + pos] = s;
        }
        return;
    }

    __shared__ _Float16 Ash[32 * KPH];

    const int tid  = threadIdx.x;
    const int lane = tid & 63;
    const int wave = tid >> 6;
    const int ln   = lane & 15;
    const int q    = lane >> 4;
    const int colBase = wave * 32;        // dedup: distinct 32-col slice per wave

    half8 WI[4][2], WM[4][2];
#pragma unroll
    for (int s = 0; s < 4; s++)
#pragma unroll
        for (int b = 0; b < 2; b++) {
            const size_t off = (size_t)(colBase + b * 16 + ln) * DD + s * 32 + q * 8;
            WI[s][b] = *(const half8*)&WiT[off];
            WM[s][b] = *(const half8*)&Wm0T[off];
        }
    float biasi[2], biasm[2];
#pragma unroll
    for (int b = 0; b < 2; b++) {
        biasi[b] = bi[colBase + b * 16 + ln];
        biasm[b] = bm0[colBase + b * 16 + ln];
    }

    const int grow = tid >> 3;     // 0..31
    const int grp  = tid & 7;      // 0..7
    const int gcol = grp * 16;

    for (int tileB = blockIdx.x - BUILDB; tileB < NFT; tileB += PREPB - BUILDB) {
        // ---- stage x tile -> Ash fp16 (coalesced 64 B/thread) ----
        const float* xr = x + ((size_t)tileB * 32 + grow) * DD + gcol;
        const float4 f0 = *(const float4*)&xr[0];
        const float4 f1 = *(const float4*)&xr[4];
        const float4 f2 = *(const float4*)&xr[8];
        const float4 f3 = *(const float4*)&xr[12];
        half8 hx0, hx1;
        hx0[0] = (_Float16)f0.x; hx0[1] = (_Float16)f0.y;
        hx0[2] = (_Float16)f0.z; hx0[3] = (_Float16)f0.w;
        hx0[4] = (_Float16)f1.x; hx0[5] = (_Float16)f1.y;
        hx0[6] = (_Float16)f1.z; hx0[7] = (_Float16)f1.w;
        hx1[0] = (_Float16)f2.x; hx1[1] = (_Float16)f2.y;
        hx1[2] = (_Float16)f2.z; hx1[3] = (_Float16)f2.w;
        hx1[4] = (_Float16)f3.x; hx1[5] = (_Float16)f3.y;
        hx1[6] = (_Float16)f3.z; hx1[7] = (_Float16)f3.w;

        __syncthreads();   // prior tile's GEMM2 Ash reads done
        *(half8*)&Ash[grow * KPH + gcol]     = hx0;
        *(half8*)&Ash[grow * KPH + gcol + 8] = hx1;
        __syncthreads();

        // ---- GEMM1: S0 = relu(x @ Wi + bi) ----
        f32x4 acc[2][2];
#pragma unroll
        for (int h = 0; h < 2; h++)
#pragma unroll
            for (int b = 0; b < 2; b++)
                acc[h][b] = (f32x4){biasi[b], biasi[b], biasi[b], biasi[b]};
#pragma unroll
        for (int s = 0; s < 4; s++) {
            const half8 a0 = *(const half8*)&Ash[(ln)      * KPH + s * 32 + q * 8];
            const half8 a1 = *(const half8*)&Ash[(16 + ln) * KPH + s * 32 + q * 8];
#pragma unroll
            for (int b = 0; b < 2; b++) {
                acc[0][b] = __builtin_amdgcn_mfma_f32_16x16x32_f16(a0, WI[s][b], acc[0][b], 0, 0, 0);
                acc[1][b] = __builtin_amdgcn_mfma_f32_16x16x32_f16(a1, WI[s][b], acc[1][b], 0, 0, 0);
            }
        }
        __syncthreads();   // all A-reads of x done before overwrite

        // S0 = relu(acc): write Sh + restage to LDS
#pragma unroll
        for (int h = 0; h < 2; h++)
#pragma unroll
            for (int b = 0; b < 2; b++) {
                const int col = colBase + b * 16 + ln;
#pragma unroll
                for (int r = 0; r < 4; r++) {
                    const int lrow = h * 16 + q * 4 + r;
                    const size_t row = (size_t)tileB * 32 + lrow;
                    const _Float16 v = (_Float16)fmaxf(acc[h][b][r], 0.f);
                    Sh[row * DD + col] = v;
                    Ash[lrow * KPH + col] = v;
                }
            }
        __syncthreads();

        // ---- GEMM2: msg0 = relu(S0 @ Wm0 + bm0) ----
        f32x4 acc2[2][2];
#pragma unroll
        for (int h = 0; h < 2; h++)
#pragma unroll
            for (int b = 0; b < 2; b++)
                acc2[h][b] = (f32x4){biasm[b], biasm[b], biasm[b], biasm[b]};
#pragma unroll
        for (int s = 0; s < 4; s++) {
            const half8 a0 = *(const half8*)&Ash[(ln)      * KPH + s * 32 + q * 8];
            const half8 a1 = *(const half8*)&Ash[(16 + ln) * KPH + s * 32 + q * 8];
#pragma unroll
            for (int b = 0; b < 2; b++) {
                acc2[0][b] = __builtin_amdgcn_mfma_f32_16x16x32_f16(a0, WM[s][b], acc2[0][b], 0, 0, 0);
                acc2[1][b] = __builtin_amdgcn_mfma_f32_16x16x32_f16(a1, WM[s][b], acc2[1][b], 0, 0, 0);
            }
        }
#pragma unroll
        for (int h = 0; h < 2; h++)
#pragma unroll
            for (int b = 0; b < 2; b++) {
                const int col = colBase + b * 16 + ln;
#pragma unroll
                for (int r = 0; r < 4; r++) {
                    const size_t row = (size_t)tileB * 32 + h * 16 + q * 4 + r;
                    msg0[row * DD + col] = (_Float16)fmaxf(acc2[h][b][r], 0.f);
                }
            }
    }
}

// ---------------------------------------------------------------------------
// fused_round_k: EXACT R2 form (best measured: ~63-68 us/round), untouched.
// Duplicated weights (wave pair shares a 64-col slice), masked 4-wide gather,
// next-tile index prefetch, (256,2). Bucket zero-initialized by host so
// speculative gather lanes past cnt hit row 0 (broadcast, cache-hot).
//   Snew = Sold + relu( segment_sum(msgIn[src],dst) @ Wu + bu )
//   if WmT:  msgOut = relu( Snew @ Wm_next + bm_next )
//   else:    write fp32 Of (final round)
// ---------------------------------------------------------------------------
__global__ __launch_bounds__(256, 2) void fused_round_k(
    const _Float16* __restrict__ msgIn,
    const int* __restrict__ cursor,
    const int* __restrict__ bucket,
    const _Float16* __restrict__ WuT, const float* __restrict__ bu_r,
    const _Float16* __restrict__ WmT, const float* __restrict__ bm_r,
    const _Float16* __restrict__ Rh,
    _Float16* __restrict__ ShOut,
    _Float16* __restrict__ msgOut,
    float* __restrict__ Of)
{
    __shared__ _Float16 Ash[32 * KPH];

    const int tid  = threadIdx.x;
    const int lane = tid & 63;
    const int wave = tid >> 6;
    const int ln   = lane & 15;
    const int q    = lane >> 4;
    const int st   = (wave & 1) * 16;
    const int colBase = (wave >> 1) * 64;

    half8 WU[4][4], WM[4][4];
#pragma unroll
    for (int s = 0; s < 4; s++) {
#pragma unroll
        for (int b = 0; b < 4; b++) {
            const size_t off = (size_t)(colBase + b * 16 + ln) * DD + s * 32 + q * 8;
            WU[s][b] = *(const half8*)&WuT[off];
            if (WmT) WM[s][b] = *(const half8*)&WmT[off];
        }
    }
    float biasu[4], biasm[4];
#pragma unroll
    for (int b = 0; b < 4; b++) {
        biasu[b] = bu_r[colBase + b * 16 + ln];
        biasm[b] = WmT ? bm_r[colBase + b * 16 + ln] : 0.f;
    }

    const int grow = tid >> 3;     // 0..31
    const int grp  = tid & 7;      // 0..7
    const int gcol = grp * 16;

    // ---- prologue: load first tile's cnt + bucket slice ----
    int cnt = 0;
    int idxr[4];
#pragma unroll
    for (int i = 0; i < 4; i++) idxr[i] = 0;
    {
        const int node = blockIdx.x * 32 + grow;
        cnt = cursor[node];
        const int ibase = node * CAP;
#pragma unroll
        for (int i = 0; i < 4; i++) idxr[i] = bucket[ibase + grp + 8 * i];
    }

    for (int tileB = blockIdx.x; tileB < NFT; tileB += gridDim.x) {
        // ---- prefetch next tile's cnt + bucket slice (resolves under MFMAs) ----
        const int nextT = tileB + gridDim.x;
        int cntN = 0;
        int idxrN[4];
#pragma unroll
        for (int i = 0; i < 4; i++) idxrN[i] = 0;
        if (nextT < NFT) {
            const int nodeN = nextT * 32 + grow;
            cntN = cursor[nodeN];
            const int ibaseN = nodeN * CAP;
#pragma unroll
            for (int i = 0; i < 4; i++) idxrN[i] = bucket[ibaseN + grp + 8 * i];
        }

        // ---- phase 1: gather + sum, masked 4-wide (no serial tail) ----
        int c = cnt;
        if (c > CAP) c = CAP;

        float a[16];
#pragma unroll
        for (int i = 0; i < 16; i++) a[i] = 0.f;

        for (int j = 0; j < c; j += 4) {
            int ix[4];
#pragma unroll
            for (int u = 0; u < 4; u++) {
                const int jj = (j + u) & 31;           // wrap keeps idxr idx valid
                int v = __shfl(idxr[jj >> 3], (lane & 56) | (jj & 7), 64);
                ix[u] = ((unsigned)v < NN) ? v : 0;    // clamp speculative lanes
            }
            half8 v[8];
#pragma unroll
            for (int u = 0; u < 4; u++) {
                v[2 * u]     = *(const half8*)&msgIn[(size_t)ix[u] * DD + gcol];
                v[2 * u + 1] = *(const half8*)&msgIn[(size_t)ix[u] * DD + gcol + 8];
            }
#pragma unroll
            for (int u = 0; u < 4; u++) {
                if (j + u < c) {                        // exec-masked accumulate
#pragma unroll
                    for (int i = 0; i < 8; i++) {
                        a[i]     += (float)v[2 * u][i];
                        a[8 + i] += (float)v[2 * u + 1][i];
                    }
                }
            }
        }

        half8 h0, h1;
#pragma unroll
        for (int i = 0; i < 8; i++) { h0[i] = (_Float16)a[i]; h1[i] = (_Float16)a[8 + i]; }

        __syncthreads();   // prior tile's last Ash reads done
        *(half8*)&Ash[grow * KPH + gcol]     = h0;
        *(half8*)&Ash[grow * KPH + gcol + 8] = h1;
        __syncthreads();

        // ---- phase 2: agg @ Wu (residual rh prefetched to overlap MFMAs) ----
        _Float16 rh[4][4];
#pragma unroll
        for (int b = 0; b < 4; b++)
#pragma unroll
            for (int r = 0; r < 4; r++) {
                const size_t row = (size_t)tileB * 32 + st + q * 4 + r;
                rh[b][r] = Rh[row * DD + colBase + b * 16 + ln];
            }

        f32x4 acc[4];
#pragma unroll
        for (int b = 0; b < 4; b++)
            acc[b] = (f32x4){biasu[b], biasu[b], biasu[b], biasu[b]};
#pragma unroll
        for (int s = 0; s < 4; s++) {
            const half8 aH = *(const half8*)&Ash[(st + ln) * KPH + s * 32 + q * 8];
#pragma unroll
            for (int b = 0; b < 4; b++)
                acc[b] = __builtin_amdgcn_mfma_f32_16x16x32_f16(aH, WU[s][b], acc[b], 0, 0, 0);
        }

        if (!WmT) {
            // final round: fp32 output only
#pragma unroll
            for (int b = 0; b < 4; b++) {
                const int col = colBase + b * 16 + ln;
#pragma unroll
                for (int r = 0; r < 4; r++) {
                    const size_t row = (size_t)tileB * 32 + st + q * 4 + r;
                    Of[row * DD + col] = fmaxf(acc[b][r], 0.f) + (float)rh[b][r];
                }
            }
            cnt = cntN;
#pragma unroll
            for (int i = 0; i < 4; i++) idxr[i] = idxrN[i];
            continue;   // loop-top barrier guards Ash reuse
        }

        __syncthreads();   // all waves done reading agg from Ash
        // Snew = Sold + relu(acc): write ShOut + restage to LDS
#pragma unroll
        for (int b = 0; b < 4; b++) {
            const int col = colBase + b * 16 + ln;
#pragma unroll
            for (int r = 0; r < 4; r++) {
                const size_t row = (size_t)tileB * 32 + st + q * 4 + r;
                const _Float16 v = (_Float16)(fmaxf(acc[b][r], 0.f) + (float)rh[b][r]);
                ShOut[row * DD + col] = v;
                Ash[(st + q * 4 + r) * KPH + col] = v;
            }
        }
        __syncthreads();

        // ---- phase 3: msgOut = relu(Snew @ Wm_next + bm_next) ----
        f32x4 acc2[4];
#pragma unroll
        for (int b = 0; b < 4; b++)
            acc2[b] = (f32x4){biasm[b], biasm[b], biasm[b], biasm[b]};
#pragma unroll
        for (int s = 0; s < 4; s++) {
            const half8 aS = *(const half8*)&Ash[(st + ln) * KPH + s * 32 + q * 8];
#pragma unroll
            for (int b = 0; b < 4; b++)
                acc2[b] = __builtin_amdgcn_mfma_f32_16x16x32_f16(aS, WM[s][b], acc2[b], 0, 0, 0);
        }
#pragma unroll
        for (int b = 0; b < 4; b++) {
            const int col = colBase + b * 16 + ln;
#pragma unroll
            for (int r = 0; r < 4; r++) {
                const size_t row = (size_t)tileB * 32 + st + q * 4 + r;
                msgOut[row * DD + col] = (_Float16)fmaxf(acc2[b][r], 0.f);
            }
        }

        cnt = cntN;
#pragma unroll
        for (int i = 0; i < 4; i++) idxr[i] = idxrN[i];
    }
}

extern "C" void kernel_launch(void* const* d_in, const int* in_sizes, int n_in,
                              void* d_out, int out_size, void* d_ws, size_t ws_size,
                              hipStream_t stream) {
    const float* x  = (const float*)d_in[0];
    const int*   ei = (const int*)d_in[1];
    const float* Wi = (const float*)d_in[2];
    const float* bi = (const float*)d_in[3];
    const float* Wm = (const float*)d_in[4];
    const float* bm = (const float*)d_in[5];
    const float* Wu = (const float*)d_in[6];
    const float* bu = (const float*)d_in[7];

    const int* src = ei;           // edge_index[0] : gather source
    const int* dst = ei + NE;      // edge_index[1] : aggregation target

    // Workspace carve (~91 MB):
    const size_t NELE = (size_t)NN * DD;
    _Float16* msgA = (_Float16*)d_ws;                    // 25.6 MB
    _Float16* msgB = msgA + NELE;                        // 25.6 MB
    _Float16* Sh   = msgB + NELE;                        // 25.6 MB
    _Float16* WT   = Sh + NELE;                          // 288 KB (9 mats)
    int* cursor = (int*)(WT + 9 * DD * DD);              // 400 KB
    int* bucket = cursor + NN;                           // 12.8 MB

    hipMemsetAsync(cursor, 0, (size_t)NN * 4, stream);
    // Zero bucket so speculative gather lanes (past cnt) read row 0
    // (broadcast, cache-hot) instead of garbage-addressed random rows.
    hipMemsetAsync(bucket, 0, (size_t)NN * CAP * 4, stream);
    wprep_k<<<9 * 128, 128, 0, stream>>>(Wi, Wm, Wu, WT);

    // concurrent bucket-build || input GEMMs, one dispatch, exact residency
    prep_k<<<PREPB, 256, 0, stream>>>(
        x, WT /*Wi*/, WT + 1 * DD * DD /*Wm0*/, bi, bm,
        Sh, msgA, src, dst, cursor, bucket);

    _Float16* mIn = msgA;
    _Float16* mOut = msgB;
    for (int r = 0; r < ROUNDS; r++) {
        const bool last = (r == ROUNDS - 1);
        fused_round_k<<<FG, 256, 0, stream>>>(
            mIn, cursor, bucket,
            WT + (size_t)(5 + r) * DD * DD, bu + (size_t)r * DD,
            last ? nullptr : WT + (size_t)(2 + r) * DD * DD,   // Wm[r+1]
            last ? nullptr : bm + (size_t)(r + 1) * DD,
            Sh, Sh, mOut,
            last ? (float*)d_out : nullptr);
        _Float16* t = mIn; mIn = mOut; mOut = t;
    }
}

// Round 8
// 307.942 us; speedup vs baseline: 1.4115x; 1.1021x over previous
//
#include <hip/hip_runtime.h>

#define NN 100000
#define NE 640000
#define DD 128
#define ROUNDS 4
#define CAP 32          // max in-degree; deg ≈ Poisson(6.4); P(any overflow) ~ 1e-9
#define NFT 3125        // NN / 32  (32-row tiles)
#define PREPB 768       // prep_k grid: 3 blocks/CU x 256 CU, exactly resident
#define BUILDB 256      // blocks [0,BUILDB): bucket build; [BUILDB,PREPB): GEMM
#define FG 512          // fused grid: 2 blocks/CU x 256 CU, exactly resident
#define KPH 136         // LDS row stride in halves (272 B; 2-way bank alias free)

typedef float f32x4 __attribute__((ext_vector_type(4)));
typedef float f32x2 __attribute__((ext_vector_type(2)));
typedef _Float16 half8 __attribute__((ext_vector_type(8)));

// fp8 e4m3 encode/decode via gfx950 HW converts (self-consistent roundtrip).
__device__ inline unsigned char to_fp8(float v) {
    return (unsigned char)(__builtin_amdgcn_cvt_pk_fp8_f32(v, 0.f, 0, 0) & 0xff);
}

// ---------------------------------------------------------------------------
// Weight prep: W (128x128 fp32 [k][n]) -> WT fp16 [n][k].
// mats: 0=Wi, 1..4=Wm[0..3], 5..8=Wu[0..3].
// ---------------------------------------------------------------------------
__global__ __launch_bounds__(128) void wprep_k(
    const float* __restrict__ Wi, const float* __restrict__ Wm,
    const float* __restrict__ Wu, _Float16* __restrict__ WT)
{
    const int mat = blockIdx.x >> 7;
    const int k   = blockIdx.x & 127;
    const int n   = threadIdx.x;
    const float* W = (mat == 0) ? Wi
                   : (mat <= 4) ? Wm + (size_t)(mat - 1) * DD * DD
                                : Wu + (size_t)(mat - 5) * DD * DD;
    WT[(size_t)mat * DD * DD + (size_t)n * DD + k] = (_Float16)W[(size_t)k * DD + n];
}

// ---------------------------------------------------------------------------
// prep_k (R7 form, verified 63 us): CONCURRENT build || GEMM block ranges.
//   blocks [0,BUILDB):       bucket build (1 atomic/edge).
//   blocks [BUILDB,PREPB):   S0 = relu(x @ Wi + bi) -> Sh (fp16);
//                            msg0 = relu(S0 @ Wm0 + bm0) -> msgA (fp8!)
// ---------------------------------------------------------------------------
__global__ __launch_bounds__(256, 3) void prep_k(
    const float* __restrict__ x,
    const _Float16* __restrict__ WiT, const _Float16* __restrict__ Wm0T,
    const float* __restrict__ bi, const float* __restrict__ bm0,
    _Float16* __restrict__ Sh, unsigned char* __restrict__ msg0,
    const int* __restrict__ src, const int* __restrict__ dst,
    int* __restrict__ cursor, int* __restrict__ bucket)
{
    if (blockIdx.x < BUILDB) {
        // ---- build-only blocks ----
        for (int e = blockIdx.x * 256 + threadIdx.x; e < NE; e += BUILDB * 256) {
            const int d = dst[e];
            const int s = src[e];
            const int pos = atomicAdd(&cursor[d], 1);
            if (pos < CAP) bucket[(long long)d * CAP + pos] = s;
        }
        return;
    }

    __shared__ _Float16 Ash[32 * KPH];

    const int tid  = threadIdx.x;
    const int lane = tid & 63;
    const int wave = tid >> 6;
    const int ln   = lane & 15;
    const int q    = lane >> 4;
    const int colBase = wave * 32;        // dedup: distinct 32-col slice per wave

    half8 WI[4][2], WM[4][2];
#pragma unroll
    for (int s = 0; s < 4; s++)
#pragma unroll
        for (int b = 0; b < 2; b++) {
            const size_t off = (size_t)(colBase + b * 16 + ln) * DD + s * 32 + q * 8;
            WI[s][b] = *(const half8*)&WiT[off];
            WM[s][b] = *(const half8*)&Wm0T[off];
        }
    float biasi[2], biasm[2];
#pragma unroll
    for (int b = 0; b < 2; b++) {
        biasi[b] = bi[colBase + b * 16 + ln];
        biasm[b] = bm0[colBase + b * 16 + ln];
    }

    const int grow = tid >> 3;     // 0..31
    const int grp  = tid & 7;      // 0..7
    const int gcol = grp * 16;

    for (int tileB = blockIdx.x - BUILDB; tileB < NFT; tileB += PREPB - BUILDB) {
        // ---- stage x tile -> Ash fp16 (coalesced 64 B/thread) ----
        const float* xr = x + ((size_t)tileB * 32 + grow) * DD + gcol;
        const float4 f0 = *(const float4*)&xr[0];
        const float4 f1 = *(const float4*)&xr[4];
        const float4 f2 = *(const float4*)&xr[8];
        const float4 f3 = *(const float4*)&xr[12];
        half8 hx0, hx1;
        hx0[0] = (_Float16)f0.x; hx0[1] = (_Float16)f0.y;
        hx0[2] = (_Float16)f0.z; hx0[3] = (_Float16)f0.w;
        hx0[4] = (_Float16)f1.x; hx0[5] = (_Float16)f1.y;
        hx0[6] = (_Float16)f1.z; hx0[7] = (_Float16)f1.w;
        hx1[0] = (_Float16)f2.x; hx1[1] = (_Float16)f2.y;
        hx1[2] = (_Float16)f2.z; hx1[3] = (_Float16)f2.w;
        hx1[4] = (_Float16)f3.x; hx1[5] = (_Float16)f3.y;
        hx1[6] = (_Float16)f3.z; hx1[7] = (_Float16)f3.w;

        __syncthreads();   // prior tile's GEMM2 Ash reads done
        *(half8*)&Ash[grow * KPH + gcol]     = hx0;
        *(half8*)&Ash[grow * KPH + gcol + 8] = hx1;
        __syncthreads();

        // ---- GEMM1: S0 = relu(x @ Wi + bi) ----
        f32x4 acc[2][2];
#pragma unroll
        for (int h = 0; h < 2; h++)
#pragma unroll
            for (int b = 0; b < 2; b++)
                acc[h][b] = (f32x4){biasi[b], biasi[b], biasi[b], biasi[b]};
#pragma unroll
        for (int s = 0; s < 4; s++) {
            const half8 a0 = *(const half8*)&Ash[(ln)      * KPH + s * 32 + q * 8];
            const half8 a1 = *(const half8*)&Ash[(16 + ln) * KPH + s * 32 + q * 8];
#pragma unroll
            for (int b = 0; b < 2; b++) {
                acc[0][b] = __builtin_amdgcn_mfma_f32_16x16x32_f16(a0, WI[s][b], acc[0][b], 0, 0, 0);
                acc[1][b] = __builtin_amdgcn_mfma_f32_16x16x32_f16(a1, WI[s][b], acc[1][b], 0, 0, 0);
            }
        }
        __syncthreads();   // all A-reads of x done before overwrite

        // S0 = relu(acc): write Sh + restage to LDS
#pragma unroll
        for (int h = 0; h < 2; h++)
#pragma unroll
            for (int b = 0; b < 2; b++) {
                const int col = colBase + b * 16 + ln;
#pragma unroll
                for (int r = 0; r < 4; r++) {
                    const int lrow = h * 16 + q * 4 + r;
                    const size_t row = (size_t)tileB * 32 + lrow;
                    const _Float16 v = (_Float16)fmaxf(acc[h][b][r], 0.f);
                    Sh[row * DD + col] = v;
                    Ash[lrow * KPH + col] = v;
                }
            }
        __syncthreads();

        // ---- GEMM2: msg0 = relu(S0 @ Wm0 + bm0), stored fp8 ----
        f32x4 acc2[2][2];
#pragma unroll
        for (int h = 0; h < 2; h++)
#pragma unroll
            for (int b = 0; b < 2; b++)
                acc2[h][b] = (f32x4){biasm[b], biasm[b], biasm[b], biasm[b]};
#pragma unroll
        for (int s = 0; s < 4; s++) {
            const half8 a0 = *(const half8*)&Ash[(ln)      * KPH + s * 32 + q * 8];
            const half8 a1 = *(const half8*)&Ash[(16 + ln) * KPH + s * 32 + q * 8];
#pragma unroll
            for (int b = 0; b < 2; b++) {
                acc2[0][b] = __builtin_amdgcn_mfma_f32_16x16x32_f16(a0, WM[s][b], acc2[0][b], 0, 0, 0);
                acc2[1][b] = __builtin_amdgcn_mfma_f32_16x16x32_f16(a1, WM[s][b], acc2[1][b], 0, 0, 0);
            }
        }
#pragma unroll
        for (int h = 0; h < 2; h++)
#pragma unroll
            for (int b = 0; b < 2; b++) {
                const int col = colBase + b * 16 + ln;
#pragma unroll
                for (int r = 0; r < 4; r++) {
                    const size_t row = (size_t)tileB * 32 + h * 16 + q * 4 + r;
                    msg0[row * DD + col] = to_fp8(fmaxf(acc2[h][b][r], 0.f));
                }
            }
    }
}

// ---------------------------------------------------------------------------
// fused_round_k: R2's verified structure; messages now fp8 (128 B/row).
// Gather: ONE 16-B load per lane per edge (was two) — bytes and load count
// both halved. Decode via v_cvt_pk_f32_fp8, sum in fp32; GEMMs stay fp16.
//   Snew = Sold + relu( segment_sum(msgIn[src],dst) @ Wu + bu )
//   if WmT:  msgOut = relu( Snew @ Wm_next + bm_next )  [fp8]
//   else:    write fp32 Of (final round)
// ---------------------------------------------------------------------------
__global__ __launch_bounds__(256, 2) void fused_round_k(
    const unsigned char* __restrict__ msgIn,
    const int* __restrict__ cursor,
    const int* __restrict__ bucket,
    const _Float16* __restrict__ WuT, const float* __restrict__ bu_r,
    const _Float16* __restrict__ WmT, const float* __restrict__ bm_r,
    const _Float16* __restrict__ Rh,
    _Float16* __restrict__ ShOut,
    unsigned char* __restrict__ msgOut,
    float* __restrict__ Of)
{
    __shared__ _Float16 Ash[32 * KPH];

    const int tid  = threadIdx.x;
    const int lane = tid & 63;
    const int wave = tid >> 6;
    const int ln   = lane & 15;
    const int q    = lane >> 4;
    const int st   = (wave & 1) * 16;
    const int colBase = (wave >> 1) * 64;

    half8 WU[4][4], WM[4][4];
#pragma unroll
    for (int s = 0; s < 4; s++) {
#pragma unroll
        for (int b = 0; b < 4; b++) {
            const size_t off = (size_t)(colBase + b * 16 + ln) * DD + s * 32 + q * 8;
            WU[s][b] = *(const half8*)&WuT[off];
            if (WmT) WM[s][b] = *(const half8*)&WmT[off];
        }
    }
    float biasu[4], biasm[4];
#pragma unroll
    for (int b = 0; b < 4; b++) {
        biasu[b] = bu_r[colBase + b * 16 + ln];
        biasm[b] = WmT ? bm_r[colBase + b * 16 + ln] : 0.f;
    }

    const int grow = tid >> 3;     // 0..31
    const int grp  = tid & 7;      // 0..7
    const int gcol = grp * 16;     // 16 fp8 columns per lane (= 16 bytes)

    // ---- prologue: load first tile's cnt + bucket slice ----
    int cnt = 0;
    int idxr[4];
#pragma unroll
    for (int i = 0; i < 4; i++) idxr[i] = 0;
    {
        const int node = blockIdx.x * 32 + grow;
        cnt = cursor[node];
        const int ibase = node * CAP;
#pragma unroll
        for (int i = 0; i < 4; i++) idxr[i] = bucket[ibase + grp + 8 * i];
    }

    for (int tileB = blockIdx.x; tileB < NFT; tileB += gridDim.x) {
        // ---- prefetch next tile's cnt + bucket slice (resolves under MFMAs) ----
        const int nextT = tileB + gridDim.x;
        int cntN = 0;
        int idxrN[4];
#pragma unroll
        for (int i = 0; i < 4; i++) idxrN[i] = 0;
        if (nextT < NFT) {
            const int nodeN = nextT * 32 + grow;
            cntN = cursor[nodeN];
            const int ibaseN = nodeN * CAP;
#pragma unroll
            for (int i = 0; i < 4; i++) idxrN[i] = bucket[ibaseN + grp + 8 * i];
        }

        // ---- phase 1: gather + sum, masked 4-wide, fp8 rows ----
        int c = cnt;
        if (c > CAP) c = CAP;

        float a[16];
#pragma unroll
        for (int i = 0; i < 16; i++) a[i] = 0.f;

        for (int j = 0; j < c; j += 4) {
            int ix[4];
#pragma unroll
            for (int u = 0; u < 4; u++) {
                const int jj = (j + u) & 31;           // wrap keeps idxr idx valid
                int v = __shfl(idxr[jj >> 3], (lane & 56) | (jj & 7), 64);
                ix[u] = ((unsigned)v < NN) ? v : 0;    // clamp speculative lanes
            }
            int4 v[4];
#pragma unroll
            for (int u = 0; u < 4; u++)
                v[u] = *(const int4*)&msgIn[(size_t)ix[u] * DD + gcol];
#pragma unroll
            for (int u = 0; u < 4; u++) {
                if (j + u < c) {                        // exec-masked accumulate
                    const int4 t = v[u];
                    const f32x2 p0 = __builtin_amdgcn_cvt_pk_f32_fp8(t.x, 0);
                    const f32x2 p1 = __builtin_amdgcn_cvt_pk_f32_fp8(t.x, 1);
                    const f32x2 p2 = __builtin_amdgcn_cvt_pk_f32_fp8(t.y, 0);
                    const f32x2 p3 = __builtin_amdgcn_cvt_pk_f32_fp8(t.y, 1);
                    const f32x2 p4 = __builtin_amdgcn_cvt_pk_f32_fp8(t.z, 0);
                    const f32x2 p5 = __builtin_amdgcn_cvt_pk_f32_fp8(t.z, 1);
                    const f32x2 p6 = __builtin_amdgcn_cvt_pk_f32_fp8(t.w, 0);
                    const f32x2 p7 = __builtin_amdgcn_cvt_pk_f32_fp8(t.w, 1);
                    a[0]  += p0.x; a[1]  += p0.y; a[2]  += p1.x; a[3]  += p1.y;
                    a[4]  += p2.x; a[5]  += p2.y; a[6]  += p3.x; a[7]  += p3.y;
                    a[8]  += p4.x; a[9]  += p4.y; a[10] += p5.x; a[11] += p5.y;
                    a[12] += p6.x; a[13] += p6.y; a[14] += p7.x; a[15] += p7.y;
                }
            }
        }

        half8 h0, h1;
#pragma unroll
        for (int i = 0; i < 8; i++) { h0[i] = (_Float16)a[i]; h1[i] = (_Float16)a[8 + i]; }

        __syncthreads();   // prior tile's last Ash reads done
        *(half8*)&Ash[grow * KPH + gcol]     = h0;
        *(half8*)&Ash[grow * KPH + gcol + 8] = h1;
        __syncthreads();

        // ---- phase 2: agg @ Wu (residual rh prefetched to overlap MFMAs) ----
        _Float16 rh[4][4];
#pragma unroll
        for (int b = 0; b < 4; b++)
#pragma unroll
            for (int r = 0; r < 4; r++) {
                const size_t row = (size_t)tileB * 32 + st + q * 4 + r;
                rh[b][r] = Rh[row * DD + colBase + b * 16 + ln];
            }

        f32x4 acc[4];
#pragma unroll
        for (int b = 0; b < 4; b++)
            acc[b] = (f32x4){biasu[b], biasu[b], biasu[b], biasu[b]};
#pragma unroll
        for (int s = 0; s < 4; s++) {
            const half8 aH = *(const half8*)&Ash[(st + ln) * KPH + s * 32 + q * 8];
#pragma unroll
            for (int b = 0; b < 4; b++)
                acc[b] = __builtin_amdgcn_mfma_f32_16x16x32_f16(aH, WU[s][b], acc[b], 0, 0, 0);
        }

        if (!WmT) {
            // final round: fp32 output only
#pragma unroll
            for (int b = 0; b < 4; b++) {
                const int col = colBase + b * 16 + ln;
#pragma unroll
                for (int r = 0; r < 4; r++) {
                    const size_t row = (size_t)tileB * 32 + st + q * 4 + r;
                    Of[row * DD + col] = fmaxf(acc[b][r], 0.f) + (float)rh[b][r];
                }
            }
            cnt = cntN;
#pragma unroll
            for (int i = 0; i < 4; i++) idxr[i] = idxrN[i];
            continue;   // loop-top barrier guards Ash reuse
        }

        __syncthreads();   // all waves done reading agg from Ash
        // Snew = Sold + relu(acc): write ShOut + restage to LDS
#pragma unroll
        for (int b = 0; b < 4; b++) {
            const int col = colBase + b * 16 + ln;
#pragma unroll
            for (int r = 0; r < 4; r++) {
                const size_t row = (size_t)tileB * 32 + st + q * 4 + r;
                const _Float16 v = (_Float16)(fmaxf(acc[b][r], 0.f) + (float)rh[b][r]);
                ShOut[row * DD + col] = v;
                Ash[(st + q * 4 + r) * KPH + col] = v;
            }
        }
        __syncthreads();

        // ---- phase 3: msgOut = relu(Snew @ Wm_next + bm_next), stored fp8 ----
        f32x4 acc2[4];
#pragma unroll
        for (int b = 0; b < 4; b++)
            acc2[b] = (f32x4){biasm[b], biasm[b], biasm[b], biasm[b]};
#pragma unroll
        for (int s = 0; s < 4; s++) {
            const half8 aS = *(const half8*)&Ash[(st + ln) * KPH + s * 32 + q * 8];
#pragma unroll
            for (int b = 0; b < 4; b++)
                acc2[b] = __builtin_amdgcn_mfma_f32_16x16x32_f16(aS, WM[s][b], acc2[b], 0, 0, 0);
        }
#pragma unroll
        for (int b = 0; b < 4; b++) {
            const int col = colBase + b * 16 + ln;
#pragma unroll
            for (int r = 0; r < 4; r++) {
                const size_t row = (size_t)tileB * 32 + st + q * 4 + r;
                msgOut[row * DD + col] = to_fp8(fmaxf(acc2[b][r], 0.f));
            }
        }

        cnt = cntN;
#pragma unroll
        for (int i = 0; i < 4; i++) idxr[i] = idxrN[i];
    }
}

extern "C" void kernel_launch(void* const* d_in, const int* in_sizes, int n_in,
                              void* d_out, int out_size, void* d_ws, size_t ws_size,
                              hipStream_t stream) {
    const float* x  = (const float*)d_in[0];
    const int*   ei = (const int*)d_in[1];
    const float* Wi = (const float*)d_in[2];
    const float* bi = (const float*)d_in[3];
    const float* Wm = (const float*)d_in[4];
    const float* bm = (const float*)d_in[5];
    const float* Wu = (const float*)d_in[6];
    const float* bu = (const float*)d_in[7];

    const int* src = ei;           // edge_index[0] : gather source
    const int* dst = ei + NE;      // edge_index[1] : aggregation target

    // Workspace carve (~65 MB):
    const size_t NELE = (size_t)NN * DD;
    unsigned char* msgA = (unsigned char*)d_ws;          // 12.8 MB (fp8)
    unsigned char* msgB = msgA + NELE;                   // 12.8 MB (fp8)
    _Float16* Sh   = (_Float16*)(msgB + NELE);           // 25.6 MB
    _Float16* WT   = Sh + NELE;                          // 288 KB (9 mats)
    int* cursor = (int*)(WT + 9 * DD * DD);              // 400 KB
    int* bucket = cursor + NN;                           // 12.8 MB

    hipMemsetAsync(cursor, 0, (size_t)NN * 4, stream);
    // Zero bucket so speculative gather lanes (past cnt) read row 0
    // (broadcast, cache-hot) instead of garbage-addressed random rows.
    hipMemsetAsync(bucket, 0, (size_t)NN * CAP * 4, stream);
    wprep_k<<<9 * 128, 128, 0, stream>>>(Wi, Wm, Wu, WT);

    // concurrent bucket-build || input GEMMs, one dispatch, exact residency
    prep_k<<<PREPB, 256, 0, stream>>>(
        x, WT /*Wi*/, WT + 1 * DD * DD /*Wm0*/, bi, bm,
        Sh, msgA, src, dst, cursor, bucket);

    unsigned char* mIn = msgA;
    unsigned char* mOut = msgB;
    for (int r = 0; r < ROUNDS; r++) {
        const bool last = (r == ROUNDS - 1);
        fused_round_k<<<FG, 256, 0, stream>>>(
            mIn, cursor, bucket,
            WT + (size_t)(5 + r) * DD * DD, bu + (size_t)r * DD,
            last ? nullptr : WT + (size_t)(2 + r) * DD * DD,   // Wm[r+1]
            last ? nullptr : bm + (size_t)(r + 1) * DD,
            Sh, Sh, mOut,
            last ? (float*)d_out : nullptr);
        unsigned char* t = mIn; mIn = mOut; mOut = t;
    }
}